// Round 1
// baseline (1613.359 us; speedup 1.0000x reference)
//
#include <hip/hip_runtime.h>
#include <math.h>

#define N_NODES 30000
#define E_EDGES 480000
#define EP (E_EDGES + N_NODES) /* 510000 edges incl self loops */
#define IN_CH 128
#define HID 32
#define HEADS 8
#define HC 256
#define BN_EPS 1e-5f
#define NEG_SLOPE 0.2f

__device__ __forceinline__ float elu_f(float x) { return x > 0.f ? x : __expf(x) - 1.f; }
__device__ __forceinline__ float lrelu_f(float x) { return x >= 0.f ? x : NEG_SLOPE * x; }

// float <-> order-preserving unsigned (for atomicMax on floats)
__device__ __forceinline__ unsigned f2ord(float f) {
    unsigned u = __float_as_uint(f);
    return (u & 0x80000000u) ? ~u : (u | 0x80000000u);
}
__device__ __forceinline__ float ord2f(unsigned u) {
    return __uint_as_float((u & 0x80000000u) ? (u ^ 0x80000000u) : ~u);
}

// ---------------- GEMM: C[M,256] = A[M,K] * B[K,256], fp32 ----------------
__global__ __launch_bounds__(256) void gemm64(const float* __restrict__ A,
                                              const float* __restrict__ B,
                                              float* __restrict__ C,
                                              int M, int K, int Ncol) {
    __shared__ float As[16][64];
    __shared__ float Bs[16][64];
    int tid = threadIdx.x;
    int tx = tid & 15, ty = tid >> 4;
    int row0 = blockIdx.y * 64, col0 = blockIdx.x * 64;
    float acc[4][4] = {};
    for (int kt = 0; kt < K; kt += 16) {
#pragma unroll
        for (int q = 0; q < 4; ++q) {
            int l = tid + q * 256;
            int r = l >> 4, k = l & 15;
            int gr = row0 + r;
            As[k][r] = (gr < M) ? A[(size_t)gr * K + kt + k] : 0.f;
            int kk = l >> 6, c = l & 63;
            Bs[kk][c] = B[(size_t)(kt + kk) * Ncol + col0 + c];
        }
        __syncthreads();
#pragma unroll
        for (int k = 0; k < 16; ++k) {
            float a[4], b[4];
#pragma unroll
            for (int i = 0; i < 4; ++i) a[i] = As[k][ty * 4 + i];
#pragma unroll
            for (int j = 0; j < 4; ++j) b[j] = Bs[k][tx * 4 + j];
#pragma unroll
            for (int i = 0; i < 4; ++i)
#pragma unroll
                for (int j = 0; j < 4; ++j) acc[i][j] += a[i] * b[j];
        }
        __syncthreads();
    }
#pragma unroll
    for (int i = 0; i < 4; ++i) {
        int gr = row0 + ty * 4 + i;
        if (gr < M) {
#pragma unroll
            for (int j = 0; j < 4; ++j)
                C[(size_t)gr * Ncol + col0 + tx * 4 + j] = acc[i][j];
        }
    }
}

// ---------------- attention logits per node ----------------
// block = 256 threads = 4 nodes (64 lanes/node); lane covers 4 channels
__global__ __launch_bounds__(256) void al_kernel(const float* __restrict__ h,
                                                 const float* __restrict__ a_src,
                                                 const float* __restrict__ a_dst,
                                                 float* __restrict__ al_s,
                                                 float* __restrict__ al_d) {
    int lane = threadIdx.x & 63;
    int n = blockIdx.x * 4 + (threadIdx.x >> 6);
    const float* row = h + (size_t)n * HC;
    int c0 = lane * 4;
    float ps = 0.f, pd = 0.f;
#pragma unroll
    for (int q = 0; q < 4; ++q) {
        float v = row[c0 + q];
        ps += v * a_src[c0 + q];
        pd += v * a_dst[c0 + q];
    }
#pragma unroll
    for (int off = 4; off >= 1; off >>= 1) {
        ps += __shfl_down(ps, off, 8);
        pd += __shfl_down(pd, off, 8);
    }
    if ((lane & 7) == 0) {
        al_s[n * HEADS + (lane >> 3)] = ps;
        al_d[n * HEADS + (lane >> 3)] = pd;
    }
}

// ---------------- edge kernels ----------------
__global__ void edge_max_kernel(const int* __restrict__ ei,
                                const float* __restrict__ al_s,
                                const float* __restrict__ al_d,
                                unsigned* __restrict__ dmax) {
    int e = blockIdx.x * blockDim.x + threadIdx.x;
    if (e >= EP) return;
    int s, d;
    if (e < E_EDGES) { s = ei[e]; d = ei[E_EDGES + e]; } else { s = d = e - E_EDGES; }
#pragma unroll
    for (int h = 0; h < HEADS; ++h) {
        float v = lrelu_f(al_s[s * HEADS + h] + al_d[d * HEADS + h]);
        atomicMax(dmax + d * HEADS + h, f2ord(v));
    }
}

__global__ void edge_exp_kernel(const int* __restrict__ ei,
                                const float* __restrict__ al_s,
                                const float* __restrict__ al_d,
                                const unsigned* __restrict__ dmax,
                                float* __restrict__ dsum,
                                float* __restrict__ ex) {
    int e = blockIdx.x * blockDim.x + threadIdx.x;
    if (e >= EP) return;
    int s, d;
    if (e < E_EDGES) { s = ei[e]; d = ei[E_EDGES + e]; } else { s = d = e - E_EDGES; }
#pragma unroll
    for (int h = 0; h < HEADS; ++h) {
        float v = lrelu_f(al_s[s * HEADS + h] + al_d[d * HEADS + h]);
        float m = ord2f(dmax[d * HEADS + h]);
        float x = __expf(v - m);
        ex[(size_t)e * HEADS + h] = x;
        atomicAdd(dsum + d * HEADS + h, x);
    }
}

// ---------------- CSR build (by dst) ----------------
__global__ void deg_kernel(const int* __restrict__ ei, int* __restrict__ deg) {
    int e = blockIdx.x * blockDim.x + threadIdx.x;
    if (e >= EP) return;
    int d = (e < E_EDGES) ? ei[E_EDGES + e] : e - E_EDGES;
    atomicAdd(deg + d, 1);
}

__global__ __launch_bounds__(1024) void scan_kernel(const int* __restrict__ deg,
                                                    int* __restrict__ row_start,
                                                    int* __restrict__ cursor) {
    __shared__ int sh[1024];
    __shared__ int carry_s;
    if (threadIdx.x == 0) carry_s = 0;
    __syncthreads();
    for (int base = 0; base < N_NODES; base += 1024) {
        int i = base + threadIdx.x;
        int v = (i < N_NODES) ? deg[i] : 0;
        sh[threadIdx.x] = v;
        __syncthreads();
        for (int off = 1; off < 1024; off <<= 1) {
            int t = (threadIdx.x >= off) ? sh[threadIdx.x - off] : 0;
            __syncthreads();
            sh[threadIdx.x] += t;
            __syncthreads();
        }
        int excl = carry_s + sh[threadIdx.x] - v;
        if (i < N_NODES) { row_start[i] = excl; cursor[i] = excl; }
        int total = sh[1023];
        __syncthreads();
        if (threadIdx.x == 0) carry_s += total;
        __syncthreads();
    }
    if (threadIdx.x == 0) row_start[N_NODES] = carry_s;
}

__global__ void scatter_kernel(const int* __restrict__ ei, int* __restrict__ cursor,
                               int* __restrict__ eid) {
    int e = blockIdx.x * blockDim.x + threadIdx.x;
    if (e >= EP) return;
    int d = (e < E_EDGES) ? ei[E_EDGES + e] : e - E_EDGES;
    int pos = atomicAdd(cursor + d, 1);
    eid[pos] = e;
}

// ---------------- aggregation: out[d,c] = sum_e alpha(e,h)*h[src,c] + bias[c] --------
__global__ __launch_bounds__(256) void aggregate_kernel(const float* __restrict__ h,
                                                        const float* __restrict__ ex,
                                                        const float* __restrict__ dsum,
                                                        const int* __restrict__ row_start,
                                                        const int* __restrict__ eid,
                                                        const int* __restrict__ ei,
                                                        const float* __restrict__ bias,
                                                        float* __restrict__ out) {
    int d = blockIdx.x;
    int c = threadIdx.x;
    __shared__ float inv[HEADS];
    if (c < HEADS) inv[c] = 1.f / dsum[d * HEADS + c];
    __syncthreads();
    int hh = c >> 5;
    float acc = 0.f;
    int beg = row_start[d], end = row_start[d + 1];
    for (int idx = beg; idx < end; ++idx) {
        int e = eid[idx];
        int s = (e < E_EDGES) ? ei[e] : e - E_EDGES;
        float alpha = ex[(size_t)e * HEADS + hh] * inv[hh];
        acc += alpha * h[(size_t)s * HC + c];
    }
    out[(size_t)d * HC + c] = acc + bias[c];
}

// ---------------- ELU (in place) + BN stats ----------------
#define BN_ROWS 128
__global__ __launch_bounds__(256) void elu_bnstat_kernel(float* __restrict__ buf,
                                                         float* __restrict__ bnsum,
                                                         float* __restrict__ bnsq) {
    int c = threadIdx.x;
    int r0 = blockIdx.x * BN_ROWS;
    int rend = min(r0 + BN_ROWS, N_NODES);
    float s = 0.f, q = 0.f;
    for (int r = r0; r < rend; ++r) {
        float v = buf[(size_t)r * HC + c];
        v = elu_f(v);
        buf[(size_t)r * HC + c] = v;
        s += v;
        q += v * v;
    }
    atomicAdd(bnsum + c, s);
    atomicAdd(bnsq + c, q);
}

__global__ void bn_fin_kernel(const float* __restrict__ bnsum, const float* __restrict__ bnsq,
                              const float* __restrict__ g, const float* __restrict__ be,
                              float* __restrict__ scale, float* __restrict__ shift) {
    int c = threadIdx.x;
    float m = bnsum[c] / (float)N_NODES;
    float var = bnsq[c] / (float)N_NODES - m * m;
    float istd = rsqrtf(var + BN_EPS);
    float sc = istd * g[c];
    scale[c] = sc;
    shift[c] = be[c] - m * sc;
}

__global__ void bn_apply_kernel(float* __restrict__ buf, const float* __restrict__ scale,
                                const float* __restrict__ shift) {
    int i = blockIdx.x * blockDim.x + threadIdx.x;
    if (i >= N_NODES * HC) return;
    int c = i & (HC - 1);
    buf[i] = buf[i] * scale[c] + shift[c];
}

// ---------------- MLP head: out[n] = elu(row @ lW1 + lb1) @ lW2 + lb2 ----------------
__global__ __launch_bounds__(256) void mlp_kernel(const float* __restrict__ in,
                                                  const float* __restrict__ lW1,
                                                  const float* __restrict__ lb1,
                                                  const float* __restrict__ lW2,
                                                  const float* __restrict__ lb2,
                                                  float* __restrict__ out) {
    int j = threadIdx.x & 31;
    int n = blockIdx.x * 8 + (threadIdx.x >> 5);
    const float* row = in + (size_t)n * HC;
    float acc = lb1[j];
    for (int c = 0; c < HC; ++c) acc += row[c] * lW1[c * HID + j];
    acc = elu_f(acc);
    float v = acc * lW2[j];
#pragma unroll
    for (int off = 16; off; off >>= 1) v += __shfl_down(v, off, 32);
    if (j == 0) out[n] = v + lb2[0];
}

extern "C" void kernel_launch(void* const* d_in, const int* in_sizes, int n_in,
                              void* d_out, int out_size, void* d_ws, size_t ws_size,
                              hipStream_t stream) {
    const float* x   = (const float*)d_in[0];
    const int*   ei  = (const int*)d_in[1];
    const float* W1  = (const float*)d_in[2];
    const float* a1s = (const float*)d_in[3];
    const float* a1d = (const float*)d_in[4];
    const float* b1  = (const float*)d_in[5];
    const float* g1  = (const float*)d_in[6];
    const float* be1 = (const float*)d_in[7];
    const float* W2  = (const float*)d_in[8];
    const float* a2s = (const float*)d_in[9];
    const float* a2d = (const float*)d_in[10];
    const float* b2  = (const float*)d_in[11];
    const float* g2  = (const float*)d_in[12];
    const float* be2 = (const float*)d_in[13];
    const float* lW1 = (const float*)d_in[14];
    const float* lb1 = (const float*)d_in[15];
    const float* lW2 = (const float*)d_in[16];
    const float* lb2 = (const float*)d_in[17];
    float* out = (float*)d_out;

    char* p = (char*)d_ws;
    auto alloc = [&](size_t bytes) {
        char* r = p;
        p += (bytes + 255) & ~(size_t)255;
        return r;
    };
    float*    f_h    = (float*)alloc((size_t)N_NODES * HC * 4);
    float*    f_out  = (float*)alloc((size_t)N_NODES * HC * 4);
    float*    f_als  = (float*)alloc((size_t)N_NODES * HEADS * 4);
    float*    f_ald  = (float*)alloc((size_t)N_NODES * HEADS * 4);
    unsigned* u_dmax = (unsigned*)alloc((size_t)N_NODES * HEADS * 4);
    float*    f_dsum = (float*)alloc((size_t)N_NODES * HEADS * 4);
    float*    f_ex   = (float*)alloc((size_t)EP * HEADS * 4);
    int*      i_deg  = (int*)alloc((size_t)N_NODES * 4);
    int*      i_rs   = (int*)alloc((size_t)(N_NODES + 1) * 4);
    int*      i_cur  = (int*)alloc((size_t)N_NODES * 4);
    int*      i_eid  = (int*)alloc((size_t)EP * 4);
    float*    f_bns  = (float*)alloc(HC * 4);
    float*    f_bnq  = (float*)alloc(HC * 4);
    float*    f_sc   = (float*)alloc(HC * 4);
    float*    f_sh   = (float*)alloc(HC * 4);

    int eb = (EP + 255) / 256;

    // ---- CSR build (same graph both layers) ----
    hipMemsetAsync(i_deg, 0, (size_t)N_NODES * 4, stream);
    deg_kernel<<<eb, 256, 0, stream>>>(ei, i_deg);
    scan_kernel<<<1, 1024, 0, stream>>>(i_deg, i_rs, i_cur);
    scatter_kernel<<<eb, 256, 0, stream>>>(ei, i_cur, i_eid);

    auto run_layer = [&](const float* xin, int K, const float* W, const float* as_,
                         const float* ad_, const float* bias, const float* gam,
                         const float* bet) {
        dim3 gg(HC / 64, (N_NODES + 63) / 64);
        gemm64<<<gg, 256, 0, stream>>>(xin, W, f_h, N_NODES, K, HC);
        al_kernel<<<N_NODES / 4, 256, 0, stream>>>(f_h, as_, ad_, f_als, f_ald);
        hipMemsetAsync(u_dmax, 0, (size_t)N_NODES * HEADS * 4, stream);
        hipMemsetAsync(f_dsum, 0, (size_t)N_NODES * HEADS * 4, stream);
        hipMemsetAsync(f_bns, 0, HC * 4, stream);
        hipMemsetAsync(f_bnq, 0, HC * 4, stream);
        edge_max_kernel<<<eb, 256, 0, stream>>>(ei, f_als, f_ald, u_dmax);
        edge_exp_kernel<<<eb, 256, 0, stream>>>(ei, f_als, f_ald, u_dmax, f_dsum, f_ex);
        aggregate_kernel<<<N_NODES, 256, 0, stream>>>(f_h, f_ex, f_dsum, i_rs, i_eid, ei,
                                                      bias, f_out);
        elu_bnstat_kernel<<<(N_NODES + BN_ROWS - 1) / BN_ROWS, 256, 0, stream>>>(f_out, f_bns,
                                                                                 f_bnq);
        bn_fin_kernel<<<1, 256, 0, stream>>>(f_bns, f_bnq, gam, bet, f_sc, f_sh);
        bn_apply_kernel<<<(N_NODES * HC + 255) / 256, 256, 0, stream>>>(f_out, f_sc, f_sh);
    };

    run_layer(x, IN_CH, W1, a1s, a1d, b1, g1, be1);
    run_layer(f_out, HC, W2, a2s, a2d, b2, g2, be2);

    mlp_kernel<<<N_NODES / 8, 256, 0, stream>>>(f_out, lW1, lb1, lW2, lb2, out);
}

// Round 2
// 747.792 us; speedup vs baseline: 2.1575x; 2.1575x over previous
//
#include <hip/hip_runtime.h>
#include <math.h>

#define N_NODES 30000
#define E_EDGES 480000
#define EP (E_EDGES + N_NODES) /* 510000 edges incl self loops */
#define IN_CH 128
#define HID 32
#define HEADS 8
#define HC 256
#define BN_EPS 1e-5f
#define NEG_SLOPE 0.2f

__device__ __forceinline__ float elu_f(float x) { return x > 0.f ? x : __expf(x) - 1.f; }
__device__ __forceinline__ float lrelu_f(float x) { return x >= 0.f ? x : NEG_SLOPE * x; }

// ---------------- GEMM: C[M,Ncol] = A'[M,K] * B[K,Ncol], fp32 ----------------
// A' = A * ascale[col] + ashift[col] if ascale != nullptr (fused BN-apply of the
// previous layer's output).
__global__ __launch_bounds__(256) void gemm64(const float* __restrict__ A,
                                              const float* __restrict__ B,
                                              float* __restrict__ C,
                                              int M, int K, int Ncol,
                                              const float* __restrict__ ascale,
                                              const float* __restrict__ ashift) {
    __shared__ float As[16][64];
    __shared__ float Bs[16][64];
    int tid = threadIdx.x;
    int tx = tid & 15, ty = tid >> 4;
    int row0 = blockIdx.y * 64, col0 = blockIdx.x * 64;
    float acc[4][4] = {};
    for (int kt = 0; kt < K; kt += 16) {
#pragma unroll
        for (int q = 0; q < 4; ++q) {
            int l = tid + q * 256;
            int r = l >> 4, k = l & 15;
            int gr = row0 + r;
            float v = (gr < M) ? A[(size_t)gr * K + kt + k] : 0.f;
            if (ascale) v = v * ascale[kt + k] + ashift[kt + k];
            As[k][r] = v;
            int kk = l >> 6, c = l & 63;
            Bs[kk][c] = B[(size_t)(kt + kk) * Ncol + col0 + c];
        }
        __syncthreads();
#pragma unroll
        for (int k = 0; k < 16; ++k) {
            float a[4], b[4];
#pragma unroll
            for (int i = 0; i < 4; ++i) a[i] = As[k][ty * 4 + i];
#pragma unroll
            for (int j = 0; j < 4; ++j) b[j] = Bs[k][tx * 4 + j];
#pragma unroll
            for (int i = 0; i < 4; ++i)
#pragma unroll
                for (int j = 0; j < 4; ++j) acc[i][j] += a[i] * b[j];
        }
        __syncthreads();
    }
#pragma unroll
    for (int i = 0; i < 4; ++i) {
        int gr = row0 + ty * 4 + i;
        if (gr < M) {
#pragma unroll
            for (int j = 0; j < 4; ++j)
                C[(size_t)gr * Ncol + col0 + tx * 4 + j] = acc[i][j];
        }
    }
}

// ---------------- attention logits per node ----------------
// block = 256 threads = 4 nodes (64 lanes/node); lane covers 4 channels
__global__ __launch_bounds__(256) void al_kernel(const float* __restrict__ h,
                                                 const float* __restrict__ a_src,
                                                 const float* __restrict__ a_dst,
                                                 float* __restrict__ al_s,
                                                 float* __restrict__ al_d) {
    int lane = threadIdx.x & 63;
    int n = blockIdx.x * 4 + (threadIdx.x >> 6);
    const float* row = h + (size_t)n * HC;
    int c0 = lane * 4;
    float ps = 0.f, pd = 0.f;
#pragma unroll
    for (int q = 0; q < 4; ++q) {
        float v = row[c0 + q];
        ps += v * a_src[c0 + q];
        pd += v * a_dst[c0 + q];
    }
#pragma unroll
    for (int off = 4; off >= 1; off >>= 1) {
        ps += __shfl_down(ps, off, 8);
        pd += __shfl_down(pd, off, 8);
    }
    if ((lane & 7) == 0) {
        al_s[n * HEADS + (lane >> 3)] = ps;
        al_d[n * HEADS + (lane >> 3)] = pd;
    }
}

// ---------------- CSR build (by dst) ----------------
__global__ void deg_kernel(const int* __restrict__ ei, int* __restrict__ deg) {
    int e = blockIdx.x * blockDim.x + threadIdx.x;
    if (e >= EP) return;
    int d = (e < E_EDGES) ? ei[E_EDGES + e] : e - E_EDGES;
    atomicAdd(deg + d, 1);
}

__global__ __launch_bounds__(1024) void scan_kernel(const int* __restrict__ deg,
                                                    int* __restrict__ row_start,
                                                    int* __restrict__ cursor) {
    __shared__ int sh[1024];
    __shared__ int carry_s;
    if (threadIdx.x == 0) carry_s = 0;
    __syncthreads();
    for (int base = 0; base < N_NODES; base += 1024) {
        int i = base + threadIdx.x;
        int v = (i < N_NODES) ? deg[i] : 0;
        sh[threadIdx.x] = v;
        __syncthreads();
        for (int off = 1; off < 1024; off <<= 1) {
            int t = (threadIdx.x >= off) ? sh[threadIdx.x - off] : 0;
            __syncthreads();
            sh[threadIdx.x] += t;
            __syncthreads();
        }
        int excl = carry_s + sh[threadIdx.x] - v;
        if (i < N_NODES) { row_start[i] = excl; cursor[i] = excl; }
        int total = sh[1023];
        __syncthreads();
        if (threadIdx.x == 0) carry_s += total;
        __syncthreads();
    }
    if (threadIdx.x == 0) row_start[N_NODES] = carry_s;
}

__global__ void scatter_kernel(const int* __restrict__ ei, int* __restrict__ cursor,
                               int* __restrict__ csr_src) {
    int e = blockIdx.x * blockDim.x + threadIdx.x;
    if (e >= EP) return;
    int s, d;
    if (e < E_EDGES) { s = ei[e]; d = ei[E_EDGES + e]; } else { s = d = e - E_EDGES; }
    int pos = atomicAdd(cursor + d, 1);
    csr_src[pos] = s;
}

// ---------------- per-dst softmax over CSR adjacency (no atomics) ----------------
// one 64-lane wave per dst node; lane = (edge_slot<<3) | head
__global__ __launch_bounds__(256) void logits_kernel(const int* __restrict__ csr_src,
                                                     const int* __restrict__ row_start,
                                                     const float* __restrict__ al_s,
                                                     const float* __restrict__ al_d,
                                                     float* __restrict__ csr_ex,
                                                     float* __restrict__ dinv) {
    int d = blockIdx.x * 4 + (threadIdx.x >> 6);
    int lane = threadIdx.x & 63;
    int h = lane & 7, eo = lane >> 3;
    int beg = row_start[d], end = row_start[d + 1];
    float ad = al_d[d * HEADS + h];
    float m = -1e30f;
    for (int i = beg + eo; i < end; i += 8) {
        int s = csr_src[i];
        m = fmaxf(m, lrelu_f(al_s[s * HEADS + h] + ad));
    }
    m = fmaxf(m, __shfl_xor(m, 8));
    m = fmaxf(m, __shfl_xor(m, 16));
    m = fmaxf(m, __shfl_xor(m, 32));
    float ssum = 0.f;
    for (int i = beg + eo; i < end; i += 8) {
        int s = csr_src[i];
        float x = __expf(lrelu_f(al_s[s * HEADS + h] + ad) - m);
        csr_ex[(size_t)i * HEADS + h] = x;
        ssum += x;
    }
    ssum += __shfl_xor(ssum, 8);
    ssum += __shfl_xor(ssum, 16);
    ssum += __shfl_xor(ssum, 32);
    if (eo == 0) dinv[d * HEADS + h] = 1.f / ssum;
}

// ---------------- aggregation + bias + ELU ----------------
__global__ __launch_bounds__(256) void aggregate_kernel(const float* __restrict__ h,
                                                        const float* __restrict__ csr_ex,
                                                        const float* __restrict__ dinv,
                                                        const int* __restrict__ row_start,
                                                        const int* __restrict__ csr_src,
                                                        const float* __restrict__ bias,
                                                        float* __restrict__ out) {
    int d = blockIdx.x;
    int c = threadIdx.x;
    __shared__ float inv[HEADS];
    if (c < HEADS) inv[c] = dinv[d * HEADS + c];
    __syncthreads();
    int hh = c >> 5;
    float acc = 0.f;
    int beg = row_start[d], end = row_start[d + 1];
    for (int idx = beg; idx < end; ++idx) {
        int s = csr_src[idx];
        float alpha = csr_ex[(size_t)idx * HEADS + hh] * inv[hh];
        acc += alpha * h[(size_t)s * HC + c];
    }
    out[(size_t)d * HC + c] = elu_f(acc + bias[c]);
}

// ---------------- BN stats (read-only) ----------------
#define BN_ROWS 128
__global__ __launch_bounds__(256) void bnstat_kernel(const float* __restrict__ buf,
                                                     float* __restrict__ bnsum,
                                                     float* __restrict__ bnsq) {
    int c = threadIdx.x;
    int r0 = blockIdx.x * BN_ROWS;
    int rend = min(r0 + BN_ROWS, N_NODES);
    float s = 0.f, q = 0.f;
    for (int r = r0; r < rend; ++r) {
        float v = buf[(size_t)r * HC + c];
        s += v;
        q += v * v;
    }
    atomicAdd(bnsum + c, s);
    atomicAdd(bnsq + c, q);
}

__global__ void bn_fin_kernel(const float* __restrict__ bnsum, const float* __restrict__ bnsq,
                              const float* __restrict__ g, const float* __restrict__ be,
                              float* __restrict__ scale, float* __restrict__ shift) {
    int c = threadIdx.x;
    float m = bnsum[c] / (float)N_NODES;
    float var = bnsq[c] / (float)N_NODES - m * m;
    float istd = rsqrtf(var + BN_EPS);
    float sc = istd * g[c];
    scale[c] = sc;
    shift[c] = be[c] - m * sc;
}

// ---------------- MLP head (BN of layer-2 output fused into the row read) ------------
__global__ __launch_bounds__(256) void mlp_kernel(const float* __restrict__ in,
                                                  const float* __restrict__ sc,
                                                  const float* __restrict__ sh,
                                                  const float* __restrict__ lW1,
                                                  const float* __restrict__ lb1,
                                                  const float* __restrict__ lW2,
                                                  const float* __restrict__ lb2,
                                                  float* __restrict__ out) {
    int j = threadIdx.x & 31;
    int n = blockIdx.x * 8 + (threadIdx.x >> 5);
    const float* row = in + (size_t)n * HC;
    float acc = lb1[j];
    for (int c = 0; c < HC; ++c) {
        float v = row[c] * sc[c] + sh[c];
        acc += v * lW1[c * HID + j];
    }
    acc = elu_f(acc);
    float v = acc * lW2[j];
#pragma unroll
    for (int off = 16; off; off >>= 1) v += __shfl_down(v, off, 32);
    if (j == 0) out[n] = v + lb2[0];
}

extern "C" void kernel_launch(void* const* d_in, const int* in_sizes, int n_in,
                              void* d_out, int out_size, void* d_ws, size_t ws_size,
                              hipStream_t stream) {
    const float* x   = (const float*)d_in[0];
    const int*   ei  = (const int*)d_in[1];
    const float* W1  = (const float*)d_in[2];
    const float* a1s = (const float*)d_in[3];
    const float* a1d = (const float*)d_in[4];
    const float* b1  = (const float*)d_in[5];
    const float* g1  = (const float*)d_in[6];
    const float* be1 = (const float*)d_in[7];
    const float* W2  = (const float*)d_in[8];
    const float* a2s = (const float*)d_in[9];
    const float* a2d = (const float*)d_in[10];
    const float* b2  = (const float*)d_in[11];
    const float* g2  = (const float*)d_in[12];
    const float* be2 = (const float*)d_in[13];
    const float* lW1 = (const float*)d_in[14];
    const float* lb1 = (const float*)d_in[15];
    const float* lW2 = (const float*)d_in[16];
    const float* lb2 = (const float*)d_in[17];
    float* out = (float*)d_out;

    char* p = (char*)d_ws;
    auto alloc = [&](size_t bytes) {
        char* r = p;
        p += (bytes + 255) & ~(size_t)255;
        return r;
    };
    float* f_h    = (float*)alloc((size_t)N_NODES * HC * 4);
    float* f_out  = (float*)alloc((size_t)N_NODES * HC * 4);
    float* f_als  = (float*)alloc((size_t)N_NODES * HEADS * 4);
    float* f_ald  = (float*)alloc((size_t)N_NODES * HEADS * 4);
    float* f_dinv = (float*)alloc((size_t)N_NODES * HEADS * 4);
    float* f_ex   = (float*)alloc((size_t)EP * HEADS * 4);
    int*   i_deg  = (int*)alloc((size_t)N_NODES * 4);
    int*   i_rs   = (int*)alloc((size_t)(N_NODES + 1) * 4);
    int*   i_cur  = (int*)alloc((size_t)N_NODES * 4);
    int*   i_src  = (int*)alloc((size_t)EP * 4);
    float* f_bns  = (float*)alloc(HC * 4);
    float* f_bnq  = (float*)alloc(HC * 4);
    float* f_sc1  = (float*)alloc(HC * 4);
    float* f_sh1  = (float*)alloc(HC * 4);
    float* f_sc2  = (float*)alloc(HC * 4);
    float* f_sh2  = (float*)alloc(HC * 4);

    int eb = (EP + 255) / 256;

    // ---- CSR build (same graph both layers) ----
    hipMemsetAsync(i_deg, 0, (size_t)N_NODES * 4, stream);
    deg_kernel<<<eb, 256, 0, stream>>>(ei, i_deg);
    scan_kernel<<<1, 1024, 0, stream>>>(i_deg, i_rs, i_cur);
    scatter_kernel<<<eb, 256, 0, stream>>>(ei, i_cur, i_src);

    auto run_layer = [&](const float* xin, int K, const float* W, const float* as_,
                         const float* ad_, const float* bias, const float* gam,
                         const float* bet, const float* in_sc, const float* in_sh,
                         float* out_sc, float* out_sh) {
        dim3 gg(HC / 64, (N_NODES + 63) / 64);
        gemm64<<<gg, 256, 0, stream>>>(xin, W, f_h, N_NODES, K, HC, in_sc, in_sh);
        al_kernel<<<N_NODES / 4, 256, 0, stream>>>(f_h, as_, ad_, f_als, f_ald);
        logits_kernel<<<N_NODES / 4, 256, 0, stream>>>(i_src, i_rs, f_als, f_ald, f_ex,
                                                       f_dinv);
        aggregate_kernel<<<N_NODES, 256, 0, stream>>>(f_h, f_ex, f_dinv, i_rs, i_src, bias,
                                                      f_out);
        hipMemsetAsync(f_bns, 0, HC * 4, stream);
        hipMemsetAsync(f_bnq, 0, HC * 4, stream);
        bnstat_kernel<<<(N_NODES + BN_ROWS - 1) / BN_ROWS, 256, 0, stream>>>(f_out, f_bns,
                                                                             f_bnq);
        bn_fin_kernel<<<1, 256, 0, stream>>>(f_bns, f_bnq, gam, bet, out_sc, out_sh);
    };

    run_layer(x, IN_CH, W1, a1s, a1d, b1, g1, be1, nullptr, nullptr, f_sc1, f_sh1);
    run_layer(f_out, HC, W2, a2s, a2d, b2, g2, be2, f_sc1, f_sh1, f_sc2, f_sh2);

    mlp_kernel<<<N_NODES / 8, 256, 0, stream>>>(f_out, f_sc2, f_sh2, lW1, lb1, lW2, lb2, out);
}

// Round 3
// 662.738 us; speedup vs baseline: 2.4344x; 1.1283x over previous
//
#include <hip/hip_runtime.h>
#include <math.h>

#define N_NODES 30000
#define E_EDGES 480000
#define EP (E_EDGES + N_NODES) /* 510000 edges incl self loops */
#define IN_CH 128
#define HID 32
#define HEADS 8
#define HC 256
#define BN_EPS 1e-5f
#define NEG_SLOPE 0.2f

__device__ __forceinline__ float elu_f(float x) { return x > 0.f ? x : __expf(x) - 1.f; }
__device__ __forceinline__ float lrelu_f(float x) { return x >= 0.f ? x : NEG_SLOPE * x; }

// ---------------- GEMM: C[M,Ncol] = A'[M,K] * B[K,Ncol], fp32 ----------------
__global__ __launch_bounds__(256) void gemm64(const float* __restrict__ A,
                                              const float* __restrict__ B,
                                              float* __restrict__ C,
                                              int M, int K, int Ncol,
                                              const float* __restrict__ ascale,
                                              const float* __restrict__ ashift) {
    __shared__ float As[16][64];
    __shared__ float Bs[16][64];
    int tid = threadIdx.x;
    int tx = tid & 15, ty = tid >> 4;
    int row0 = blockIdx.y * 64, col0 = blockIdx.x * 64;
    float acc[4][4] = {};
    for (int kt = 0; kt < K; kt += 16) {
#pragma unroll
        for (int q = 0; q < 4; ++q) {
            int l = tid + q * 256;
            int r = l >> 4, k = l & 15;
            int gr = row0 + r;
            float v = (gr < M) ? A[(size_t)gr * K + kt + k] : 0.f;
            if (ascale) v = v * ascale[kt + k] + ashift[kt + k];
            As[k][r] = v;
            int kk = l >> 6, c = l & 63;
            Bs[kk][c] = B[(size_t)(kt + kk) * Ncol + col0 + c];
        }
        __syncthreads();
#pragma unroll
        for (int k = 0; k < 16; ++k) {
            float a[4], b[4];
#pragma unroll
            for (int i = 0; i < 4; ++i) a[i] = As[k][ty * 4 + i];
#pragma unroll
            for (int j = 0; j < 4; ++j) b[j] = Bs[k][tx * 4 + j];
#pragma unroll
            for (int i = 0; i < 4; ++i)
#pragma unroll
                for (int j = 0; j < 4; ++j) acc[i][j] += a[i] * b[j];
        }
        __syncthreads();
    }
#pragma unroll
    for (int i = 0; i < 4; ++i) {
        int gr = row0 + ty * 4 + i;
        if (gr < M) {
#pragma unroll
            for (int j = 0; j < 4; ++j)
                C[(size_t)gr * Ncol + col0 + tx * 4 + j] = acc[i][j];
        }
    }
}

// ---------------- attention logits per node ----------------
__global__ __launch_bounds__(256) void al_kernel(const float* __restrict__ h,
                                                 const float* __restrict__ a_src,
                                                 const float* __restrict__ a_dst,
                                                 float* __restrict__ al_s,
                                                 float* __restrict__ al_d) {
    int lane = threadIdx.x & 63;
    int n = blockIdx.x * 4 + (threadIdx.x >> 6);
    const float* row = h + (size_t)n * HC;
    int c0 = lane * 4;
    float ps = 0.f, pd = 0.f;
#pragma unroll
    for (int q = 0; q < 4; ++q) {
        float v = row[c0 + q];
        ps += v * a_src[c0 + q];
        pd += v * a_dst[c0 + q];
    }
#pragma unroll
    for (int off = 4; off >= 1; off >>= 1) {
        ps += __shfl_down(ps, off, 8);
        pd += __shfl_down(pd, off, 8);
    }
    if ((lane & 7) == 0) {
        al_s[n * HEADS + (lane >> 3)] = ps;
        al_d[n * HEADS + (lane >> 3)] = pd;
    }
}

// ---------------- CSR build (by dst) ----------------
__global__ void deg_kernel(const int* __restrict__ ei, int* __restrict__ deg) {
    int e = blockIdx.x * blockDim.x + threadIdx.x;
    if (e >= EP) return;
    int d = (e < E_EDGES) ? ei[E_EDGES + e] : e - E_EDGES;
    atomicAdd(deg + d, 1);
}

__global__ __launch_bounds__(1024) void scan_kernel(const int* __restrict__ deg,
                                                    int* __restrict__ row_start,
                                                    int* __restrict__ cursor) {
    __shared__ int sh[1024];
    __shared__ int carry_s;
    if (threadIdx.x == 0) carry_s = 0;
    __syncthreads();
    for (int base = 0; base < N_NODES; base += 1024) {
        int i = base + threadIdx.x;
        int v = (i < N_NODES) ? deg[i] : 0;
        sh[threadIdx.x] = v;
        __syncthreads();
        for (int off = 1; off < 1024; off <<= 1) {
            int t = (threadIdx.x >= off) ? sh[threadIdx.x - off] : 0;
            __syncthreads();
            sh[threadIdx.x] += t;
            __syncthreads();
        }
        int excl = carry_s + sh[threadIdx.x] - v;
        if (i < N_NODES) { row_start[i] = excl; cursor[i] = excl; }
        int total = sh[1023];
        __syncthreads();
        if (threadIdx.x == 0) carry_s += total;
        __syncthreads();
    }
    if (threadIdx.x == 0) row_start[N_NODES] = carry_s;
}

__global__ void scatter_kernel(const int* __restrict__ ei, int* __restrict__ cursor,
                               int* __restrict__ csr_src) {
    int e = blockIdx.x * blockDim.x + threadIdx.x;
    if (e >= EP) return;
    int s, d;
    if (e < E_EDGES) { s = ei[e]; d = ei[E_EDGES + e]; } else { s = d = e - E_EDGES; }
    int pos = atomicAdd(cursor + d, 1);
    csr_src[pos] = s;
}

// ---------------- per-dst softmax over CSR adjacency (no atomics) ----------------
__global__ __launch_bounds__(256) void logits_kernel(const int* __restrict__ csr_src,
                                                     const int* __restrict__ row_start,
                                                     const float* __restrict__ al_s,
                                                     const float* __restrict__ al_d,
                                                     float* __restrict__ csr_ex,
                                                     float* __restrict__ dinv) {
    int d = blockIdx.x * 4 + (threadIdx.x >> 6);
    int lane = threadIdx.x & 63;
    int h = lane & 7, eo = lane >> 3;
    int beg = row_start[d], end = row_start[d + 1];
    float ad = al_d[d * HEADS + h];
    float m = -1e30f;
    for (int i = beg + eo; i < end; i += 8) {
        int s = csr_src[i];
        m = fmaxf(m, lrelu_f(al_s[s * HEADS + h] + ad));
    }
    m = fmaxf(m, __shfl_xor(m, 8));
    m = fmaxf(m, __shfl_xor(m, 16));
    m = fmaxf(m, __shfl_xor(m, 32));
    float ssum = 0.f;
    for (int i = beg + eo; i < end; i += 8) {
        int s = csr_src[i];
        float x = __expf(lrelu_f(al_s[s * HEADS + h] + ad) - m);
        csr_ex[(size_t)i * HEADS + h] = x;
        ssum += x;
    }
    ssum += __shfl_xor(ssum, 8);
    ssum += __shfl_xor(ssum, 16);
    ssum += __shfl_xor(ssum, 32);
    if (eo == 0) dinv[d * HEADS + h] = 1.f / ssum;
}

// ---------------- aggregation + bias + ELU ----------------
// one 64-lane wave per dst node; lane owns 4 channels (float4); edge loop
// unrolled x4 so 4 row-gathers are in flight per lane (MLP, not latency-serial)
__global__ __launch_bounds__(256) void aggregate_kernel(const float4* __restrict__ h4,
                                                        const float* __restrict__ csr_ex,
                                                        const float* __restrict__ dinv,
                                                        const int* __restrict__ row_start,
                                                        const int* __restrict__ csr_src,
                                                        const float4* __restrict__ bias4,
                                                        float4* __restrict__ out4) {
    int d = blockIdx.x * 4 + (threadIdx.x >> 6);
    int lane = threadIdx.x & 63;
    int head = lane >> 3;  // 4 consecutive channels never straddle a head (32ch)
    int beg = row_start[d], end = row_start[d + 1];
    float inv = dinv[d * HEADS + head];
    float4 acc = make_float4(0.f, 0.f, 0.f, 0.f);
    int i = beg;
    for (; i + 4 <= end; i += 4) {
        int s0 = csr_src[i + 0];
        int s1 = csr_src[i + 1];
        int s2 = csr_src[i + 2];
        int s3 = csr_src[i + 3];
        float a0 = csr_ex[(size_t)(i + 0) * HEADS + head];
        float a1 = csr_ex[(size_t)(i + 1) * HEADS + head];
        float a2 = csr_ex[(size_t)(i + 2) * HEADS + head];
        float a3 = csr_ex[(size_t)(i + 3) * HEADS + head];
        float4 v0 = h4[(size_t)s0 * 64 + lane];
        float4 v1 = h4[(size_t)s1 * 64 + lane];
        float4 v2 = h4[(size_t)s2 * 64 + lane];
        float4 v3 = h4[(size_t)s3 * 64 + lane];
        acc.x += a0 * v0.x + a1 * v1.x + a2 * v2.x + a3 * v3.x;
        acc.y += a0 * v0.y + a1 * v1.y + a2 * v2.y + a3 * v3.y;
        acc.z += a0 * v0.z + a1 * v1.z + a2 * v2.z + a3 * v3.z;
        acc.w += a0 * v0.w + a1 * v1.w + a2 * v2.w + a3 * v3.w;
    }
    for (; i < end; ++i) {
        int s = csr_src[i];
        float a = csr_ex[(size_t)i * HEADS + head];
        float4 v = h4[(size_t)s * 64 + lane];
        acc.x += a * v.x;
        acc.y += a * v.y;
        acc.z += a * v.z;
        acc.w += a * v.w;
    }
    float4 b = bias4[lane];
    float4 r;
    r.x = elu_f(acc.x * inv + b.x);
    r.y = elu_f(acc.y * inv + b.y);
    r.z = elu_f(acc.z * inv + b.z);
    r.w = elu_f(acc.w * inv + b.w);
    out4[(size_t)d * 64 + lane] = r;
}

// ---------------- BN stats (read-only) ----------------
#define BN_ROWS 128
__global__ __launch_bounds__(256) void bnstat_kernel(const float* __restrict__ buf,
                                                     float* __restrict__ bnsum,
                                                     float* __restrict__ bnsq) {
    int c = threadIdx.x;
    int r0 = blockIdx.x * BN_ROWS;
    int rend = min(r0 + BN_ROWS, N_NODES);
    float s = 0.f, q = 0.f;
    for (int r = r0; r < rend; ++r) {
        float v = buf[(size_t)r * HC + c];
        s += v;
        q += v * v;
    }
    atomicAdd(bnsum + c, s);
    atomicAdd(bnsq + c, q);
}

__global__ void bn_fin_kernel(const float* __restrict__ bnsum, const float* __restrict__ bnsq,
                              const float* __restrict__ g, const float* __restrict__ be,
                              float* __restrict__ scale, float* __restrict__ shift) {
    int c = threadIdx.x;
    float m = bnsum[c] / (float)N_NODES;
    float var = bnsq[c] / (float)N_NODES - m * m;
    float istd = rsqrtf(var + BN_EPS);
    float sc = istd * g[c];
    scale[c] = sc;
    shift[c] = be[c] - m * sc;
}

// ---------------- MLP head (BN of layer-2 output fused into the row read) ------------
__global__ __launch_bounds__(256) void mlp_kernel(const float* __restrict__ in,
                                                  const float* __restrict__ sc,
                                                  const float* __restrict__ sh,
                                                  const float* __restrict__ lW1,
                                                  const float* __restrict__ lb1,
                                                  const float* __restrict__ lW2,
                                                  const float* __restrict__ lb2,
                                                  float* __restrict__ out) {
    int j = threadIdx.x & 31;
    int n = blockIdx.x * 8 + (threadIdx.x >> 5);
    const float* row = in + (size_t)n * HC;
    float acc = lb1[j];
    for (int c = 0; c < HC; ++c) {
        float v = row[c] * sc[c] + sh[c];
        acc += v * lW1[c * HID + j];
    }
    acc = elu_f(acc);
    float v = acc * lW2[j];
#pragma unroll
    for (int off = 16; off; off >>= 1) v += __shfl_down(v, off, 32);
    if (j == 0) out[n] = v + lb2[0];
}

extern "C" void kernel_launch(void* const* d_in, const int* in_sizes, int n_in,
                              void* d_out, int out_size, void* d_ws, size_t ws_size,
                              hipStream_t stream) {
    const float* x   = (const float*)d_in[0];
    const int*   ei  = (const int*)d_in[1];
    const float* W1  = (const float*)d_in[2];
    const float* a1s = (const float*)d_in[3];
    const float* a1d = (const float*)d_in[4];
    const float* b1  = (const float*)d_in[5];
    const float* g1  = (const float*)d_in[6];
    const float* be1 = (const float*)d_in[7];
    const float* W2  = (const float*)d_in[8];
    const float* a2s = (const float*)d_in[9];
    const float* a2d = (const float*)d_in[10];
    const float* b2  = (const float*)d_in[11];
    const float* g2  = (const float*)d_in[12];
    const float* be2 = (const float*)d_in[13];
    const float* lW1 = (const float*)d_in[14];
    const float* lb1 = (const float*)d_in[15];
    const float* lW2 = (const float*)d_in[16];
    const float* lb2 = (const float*)d_in[17];
    float* out = (float*)d_out;

    char* p = (char*)d_ws;
    auto alloc = [&](size_t bytes) {
        char* r = p;
        p += (bytes + 255) & ~(size_t)255;
        return r;
    };
    float* f_h    = (float*)alloc((size_t)N_NODES * HC * 4);
    float* f_out  = (float*)alloc((size_t)N_NODES * HC * 4);
    float* f_als  = (float*)alloc((size_t)N_NODES * HEADS * 4);
    float* f_ald  = (float*)alloc((size_t)N_NODES * HEADS * 4);
    float* f_dinv = (float*)alloc((size_t)N_NODES * HEADS * 4);
    float* f_ex   = (float*)alloc((size_t)EP * HEADS * 4);
    int*   i_deg  = (int*)alloc((size_t)N_NODES * 4);
    int*   i_rs   = (int*)alloc((size_t)(N_NODES + 1) * 4);
    int*   i_cur  = (int*)alloc((size_t)N_NODES * 4);
    int*   i_src  = (int*)alloc((size_t)EP * 4);
    float* f_bns  = (float*)alloc(HC * 4);
    float* f_bnq  = (float*)alloc(HC * 4);
    float* f_sc1  = (float*)alloc(HC * 4);
    float* f_sh1  = (float*)alloc(HC * 4);
    float* f_sc2  = (float*)alloc(HC * 4);
    float* f_sh2  = (float*)alloc(HC * 4);

    int eb = (EP + 255) / 256;

    // ---- CSR build (same graph both layers) ----
    hipMemsetAsync(i_deg, 0, (size_t)N_NODES * 4, stream);
    deg_kernel<<<eb, 256, 0, stream>>>(ei, i_deg);
    scan_kernel<<<1, 1024, 0, stream>>>(i_deg, i_rs, i_cur);
    scatter_kernel<<<eb, 256, 0, stream>>>(ei, i_cur, i_src);

    auto run_layer = [&](const float* xin, int K, const float* W, const float* as_,
                         const float* ad_, const float* bias, const float* gam,
                         const float* bet, const float* in_sc, const float* in_sh,
                         float* out_sc, float* out_sh) {
        dim3 gg(HC / 64, (N_NODES + 63) / 64);
        gemm64<<<gg, 256, 0, stream>>>(xin, W, f_h, N_NODES, K, HC, in_sc, in_sh);
        al_kernel<<<N_NODES / 4, 256, 0, stream>>>(f_h, as_, ad_, f_als, f_ald);
        logits_kernel<<<N_NODES / 4, 256, 0, stream>>>(i_src, i_rs, f_als, f_ald, f_ex,
                                                       f_dinv);
        aggregate_kernel<<<N_NODES / 4, 256, 0, stream>>>((const float4*)f_h, f_ex, f_dinv,
                                                          i_rs, i_src, (const float4*)bias,
                                                          (float4*)f_out);
        hipMemsetAsync(f_bns, 0, HC * 4, stream);
        hipMemsetAsync(f_bnq, 0, HC * 4, stream);
        bnstat_kernel<<<(N_NODES + BN_ROWS - 1) / BN_ROWS, 256, 0, stream>>>(f_out, f_bns,
                                                                             f_bnq);
        bn_fin_kernel<<<1, 256, 0, stream>>>(f_bns, f_bnq, gam, bet, out_sc, out_sh);
    };

    run_layer(x, IN_CH, W1, a1s, a1d, b1, g1, be1, nullptr, nullptr, f_sc1, f_sh1);
    run_layer(f_out, HC, W2, a2s, a2d, b2, g2, be2, f_sc1, f_sh1, f_sc2, f_sh2);

    mlp_kernel<<<N_NODES / 8, 256, 0, stream>>>(f_out, f_sc2, f_sh2, lW1, lb1, lW2, lb2, out);
}

// Round 4
// 503.790 us; speedup vs baseline: 3.2024x; 1.3155x over previous
//
#include <hip/hip_runtime.h>
#include <math.h>

#define N_NODES 30000
#define E_EDGES 480000
#define EP (E_EDGES + N_NODES) /* 510000 edges incl self loops */
#define IN_CH 128
#define HID 32
#define HEADS 8
#define HC 256
#define BN_EPS 1e-5f
#define NEG_SLOPE 0.2f

typedef __attribute__((ext_vector_type(8))) short bf16x8;
typedef __attribute__((ext_vector_type(4))) float f32x4;

__device__ __forceinline__ float elu_f(float x) { return x > 0.f ? x : __expf(x) - 1.f; }
__device__ __forceinline__ float lrelu_f(float x) { return x >= 0.f ? x : NEG_SLOPE * x; }
__device__ __forceinline__ float bf2f(unsigned short u) {
    return __uint_as_float(((unsigned)u) << 16);
}
__device__ __forceinline__ unsigned short f2bf(float f) {
    unsigned u = __float_as_uint(f);
    return (unsigned short)((u + 0x7fffu + ((u >> 16) & 1u)) >> 16);
}

// ---------------- fp32 -> bf16 conversion (optional fused BN apply) ----------------
__global__ void cvt_kernel(const float* __restrict__ in, const float* __restrict__ sc,
                           const float* __restrict__ sh, unsigned short* __restrict__ out,
                           int total) {
    int i = blockIdx.x * 256 + threadIdx.x;
    if (i >= total) return;
    float v = in[i];
    if (sc) {
        int c = i & (HC - 1);
        v = v * sc[c] + sh[c];
    }
    out[i] = f2bf(v);
}

// ---------------- W[k][n] fp32 -> Wt[n][k] bf16 ----------------
__global__ void wt_kernel(const float* __restrict__ W, unsigned short* __restrict__ Wt,
                          int K) {
    int i = blockIdx.x * 256 + threadIdx.x;
    if (i >= K * HC) return;
    int k = i >> 8, n = i & (HC - 1);
    Wt[(size_t)n * K + k] = f2bf(W[i]);
}

// ---------------- MFMA GEMM: C[M,256] = A[M,K] * Wt^T, bf16 in, bf16 out -----------
// block = 256 thr = 4 waves; tile 64(M) x 256(N), BK=32.
// LDS rows padded to 40 bf16 (80 B pitch = 16B aligned, bank stride 20 -> 2-way only)
__global__ __launch_bounds__(256) void gemm_mfma(const unsigned short* __restrict__ A,
                                                 const unsigned short* __restrict__ Bt,
                                                 unsigned short* __restrict__ C,
                                                 int M, int K) {
    __shared__ __align__(16) unsigned short As[64][40];
    __shared__ __align__(16) unsigned short Bs[256][40];
    int tid = threadIdx.x;
    int wave = tid >> 6, lane = tid & 63;
    int m = lane & 15, q = lane >> 4;
    int row0 = blockIdx.x * 64;
    f32x4 acc[16];
#pragma unroll
    for (int i = 0; i < 16; ++i) acc[i] = (f32x4){0.f, 0.f, 0.f, 0.f};
    int ar = tid >> 2, aseg = tid & 3;
    for (int k0 = 0; k0 < K; k0 += 32) {
        uint4 av = make_uint4(0u, 0u, 0u, 0u);
        int gr = row0 + ar;
        if (gr < M) av = *(const uint4*)(A + (size_t)gr * K + k0 + aseg * 8);
        *(uint4*)(&As[ar][aseg * 8]) = av;
        const unsigned short* bp = Bt + (size_t)tid * K + k0;
#pragma unroll
        for (int sg = 0; sg < 4; ++sg)
            *(uint4*)(&Bs[tid][sg * 8]) = *(const uint4*)(bp + sg * 8);
        __syncthreads();
        bf16x8 a = *(const bf16x8*)(&As[wave * 16 + m][q * 8]);
#pragma unroll
        for (int nt = 0; nt < 16; ++nt) {
            bf16x8 b = *(const bf16x8*)(&Bs[nt * 16 + m][q * 8]);
            acc[nt] = __builtin_amdgcn_mfma_f32_16x16x32_bf16(a, b, acc[nt], 0, 0, 0);
        }
        __syncthreads();
    }
#pragma unroll
    for (int nt = 0; nt < 16; ++nt) {
#pragma unroll
        for (int r = 0; r < 4; ++r) {
            int grow = row0 + wave * 16 + q * 4 + r;
            if (grow < M) C[(size_t)grow * HC + nt * 16 + m] = f2bf(acc[nt][r]);
        }
    }
}

// ---------------- attention logits per node (bf16 h) ----------------
__global__ __launch_bounds__(256) void al_kernel(const unsigned short* __restrict__ h,
                                                 const float* __restrict__ a_src,
                                                 const float* __restrict__ a_dst,
                                                 float* __restrict__ al_s,
                                                 float* __restrict__ al_d) {
    int lane = threadIdx.x & 63;
    int n = blockIdx.x * 4 + (threadIdx.x >> 6);
    const ushort4* row = (const ushort4*)(h + (size_t)n * HC);
    ushort4 rv = row[lane];
    int c0 = lane * 4;
    float ps = 0.f, pd = 0.f;
    float v0 = bf2f(rv.x), v1 = bf2f(rv.y), v2 = bf2f(rv.z), v3 = bf2f(rv.w);
    ps = v0 * a_src[c0] + v1 * a_src[c0 + 1] + v2 * a_src[c0 + 2] + v3 * a_src[c0 + 3];
    pd = v0 * a_dst[c0] + v1 * a_dst[c0 + 1] + v2 * a_dst[c0 + 2] + v3 * a_dst[c0 + 3];
#pragma unroll
    for (int off = 4; off >= 1; off >>= 1) {
        ps += __shfl_down(ps, off, 8);
        pd += __shfl_down(pd, off, 8);
    }
    if ((lane & 7) == 0) {
        al_s[n * HEADS + (lane >> 3)] = ps;
        al_d[n * HEADS + (lane >> 3)] = pd;
    }
}

// ---------------- CSR build (by dst) ----------------
__global__ void deg_kernel(const int* __restrict__ ei, int* __restrict__ deg) {
    int e = blockIdx.x * blockDim.x + threadIdx.x;
    if (e >= EP) return;
    int d = (e < E_EDGES) ? ei[E_EDGES + e] : e - E_EDGES;
    atomicAdd(deg + d, 1);
}

__global__ __launch_bounds__(1024) void scan_kernel(const int* __restrict__ deg,
                                                    int* __restrict__ row_start,
                                                    int* __restrict__ cursor) {
    __shared__ int sh[1024];
    __shared__ int carry_s;
    if (threadIdx.x == 0) carry_s = 0;
    __syncthreads();
    for (int base = 0; base < N_NODES; base += 1024) {
        int i = base + threadIdx.x;
        int v = (i < N_NODES) ? deg[i] : 0;
        sh[threadIdx.x] = v;
        __syncthreads();
        for (int off = 1; off < 1024; off <<= 1) {
            int t = (threadIdx.x >= off) ? sh[threadIdx.x - off] : 0;
            __syncthreads();
            sh[threadIdx.x] += t;
            __syncthreads();
        }
        int excl = carry_s + sh[threadIdx.x] - v;
        if (i < N_NODES) { row_start[i] = excl; cursor[i] = excl; }
        int total = sh[1023];
        __syncthreads();
        if (threadIdx.x == 0) carry_s += total;
        __syncthreads();
    }
    if (threadIdx.x == 0) row_start[N_NODES] = carry_s;
}

__global__ void scatter_kernel(const int* __restrict__ ei, int* __restrict__ cursor,
                               int* __restrict__ csr_src) {
    int e = blockIdx.x * blockDim.x + threadIdx.x;
    if (e >= EP) return;
    int s, d;
    if (e < E_EDGES) { s = ei[e]; d = ei[E_EDGES + e]; } else { s = d = e - E_EDGES; }
    int pos = atomicAdd(cursor + d, 1);
    csr_src[pos] = s;
}

// ---------------- per-dst softmax over CSR adjacency (no atomics) ----------------
__global__ __launch_bounds__(256) void logits_kernel(const int* __restrict__ csr_src,
                                                     const int* __restrict__ row_start,
                                                     const float* __restrict__ al_s,
                                                     const float* __restrict__ al_d,
                                                     float* __restrict__ csr_ex,
                                                     float* __restrict__ dinv) {
    int d = blockIdx.x * 4 + (threadIdx.x >> 6);
    int lane = threadIdx.x & 63;
    int h = lane & 7, eo = lane >> 3;
    int beg = row_start[d], end = row_start[d + 1];
    float ad = al_d[d * HEADS + h];
    float m = -1e30f;
    for (int i = beg + eo; i < end; i += 8) {
        int s = csr_src[i];
        m = fmaxf(m, lrelu_f(al_s[s * HEADS + h] + ad));
    }
    m = fmaxf(m, __shfl_xor(m, 8));
    m = fmaxf(m, __shfl_xor(m, 16));
    m = fmaxf(m, __shfl_xor(m, 32));
    float ssum = 0.f;
    for (int i = beg + eo; i < end; i += 8) {
        int s = csr_src[i];
        float x = __expf(lrelu_f(al_s[s * HEADS + h] + ad) - m);
        csr_ex[(size_t)i * HEADS + h] = x;
        ssum += x;
    }
    ssum += __shfl_xor(ssum, 8);
    ssum += __shfl_xor(ssum, 16);
    ssum += __shfl_xor(ssum, 32);
    if (eo == 0) dinv[d * HEADS + h] = 1.f / ssum;
}

// ---------------- aggregation + bias + ELU (bf16 h gather) ----------------
__global__ __launch_bounds__(256) void aggregate_kernel(const ushort4* __restrict__ h4,
                                                        const float* __restrict__ csr_ex,
                                                        const float* __restrict__ dinv,
                                                        const int* __restrict__ row_start,
                                                        const int* __restrict__ csr_src,
                                                        const float4* __restrict__ bias4,
                                                        float4* __restrict__ out4) {
    int d = blockIdx.x * 4 + (threadIdx.x >> 6);
    int lane = threadIdx.x & 63;
    int head = lane >> 3;
    int beg = row_start[d], end = row_start[d + 1];
    float inv = dinv[d * HEADS + head];
    float4 acc = make_float4(0.f, 0.f, 0.f, 0.f);
    int i = beg;
    for (; i + 4 <= end; i += 4) {
        int s0 = csr_src[i + 0];
        int s1 = csr_src[i + 1];
        int s2 = csr_src[i + 2];
        int s3 = csr_src[i + 3];
        float a0 = csr_ex[(size_t)(i + 0) * HEADS + head];
        float a1 = csr_ex[(size_t)(i + 1) * HEADS + head];
        float a2 = csr_ex[(size_t)(i + 2) * HEADS + head];
        float a3 = csr_ex[(size_t)(i + 3) * HEADS + head];
        ushort4 v0 = h4[(size_t)s0 * 64 + lane];
        ushort4 v1 = h4[(size_t)s1 * 64 + lane];
        ushort4 v2 = h4[(size_t)s2 * 64 + lane];
        ushort4 v3 = h4[(size_t)s3 * 64 + lane];
        acc.x += a0 * bf2f(v0.x) + a1 * bf2f(v1.x) + a2 * bf2f(v2.x) + a3 * bf2f(v3.x);
        acc.y += a0 * bf2f(v0.y) + a1 * bf2f(v1.y) + a2 * bf2f(v2.y) + a3 * bf2f(v3.y);
        acc.z += a0 * bf2f(v0.z) + a1 * bf2f(v1.z) + a2 * bf2f(v2.z) + a3 * bf2f(v3.z);
        acc.w += a0 * bf2f(v0.w) + a1 * bf2f(v1.w) + a2 * bf2f(v2.w) + a3 * bf2f(v3.w);
    }
    for (; i < end; ++i) {
        int s = csr_src[i];
        float a = csr_ex[(size_t)i * HEADS + head];
        ushort4 v = h4[(size_t)s * 64 + lane];
        acc.x += a * bf2f(v.x);
        acc.y += a * bf2f(v.y);
        acc.z += a * bf2f(v.z);
        acc.w += a * bf2f(v.w);
    }
    float4 b = bias4[lane];
    float4 r;
    r.x = elu_f(acc.x * inv + b.x);
    r.y = elu_f(acc.y * inv + b.y);
    r.z = elu_f(acc.z * inv + b.z);
    r.w = elu_f(acc.w * inv + b.w);
    out4[(size_t)d * 64 + lane] = r;
}

// ---------------- BN stats (read-only) ----------------
#define BN_ROWS 128
__global__ __launch_bounds__(256) void bnstat_kernel(const float* __restrict__ buf,
                                                     float* __restrict__ bnsum,
                                                     float* __restrict__ bnsq) {
    int c = threadIdx.x;
    int r0 = blockIdx.x * BN_ROWS;
    int rend = min(r0 + BN_ROWS, N_NODES);
    float s = 0.f, q = 0.f;
    for (int r = r0; r < rend; ++r) {
        float v = buf[(size_t)r * HC + c];
        s += v;
        q += v * v;
    }
    atomicAdd(bnsum + c, s);
    atomicAdd(bnsq + c, q);
}

__global__ void bn_fin_kernel(const float* __restrict__ bnsum, const float* __restrict__ bnsq,
                              const float* __restrict__ g, const float* __restrict__ be,
                              float* __restrict__ scale, float* __restrict__ shift) {
    int c = threadIdx.x;
    float m = bnsum[c] / (float)N_NODES;
    float var = bnsq[c] / (float)N_NODES - m * m;
    float istd = rsqrtf(var + BN_EPS);
    float sc = istd * g[c];
    scale[c] = sc;
    shift[c] = be[c] - m * sc;
}

// ---------------- MLP head (BN of layer-2 output fused into the row read) ------------
__global__ __launch_bounds__(256) void mlp_kernel(const float* __restrict__ in,
                                                  const float* __restrict__ sc,
                                                  const float* __restrict__ sh,
                                                  const float* __restrict__ lW1,
                                                  const float* __restrict__ lb1,
                                                  const float* __restrict__ lW2,
                                                  const float* __restrict__ lb2,
                                                  float* __restrict__ out) {
    int j = threadIdx.x & 31;
    int n = blockIdx.x * 8 + (threadIdx.x >> 5);
    const float* row = in + (size_t)n * HC;
    float acc = lb1[j];
    for (int c = 0; c < HC; ++c) {
        float v = row[c] * sc[c] + sh[c];
        acc += v * lW1[c * HID + j];
    }
    acc = elu_f(acc);
    float v = acc * lW2[j];
#pragma unroll
    for (int off = 16; off; off >>= 1) v += __shfl_down(v, off, 32);
    if (j == 0) out[n] = v + lb2[0];
}

extern "C" void kernel_launch(void* const* d_in, const int* in_sizes, int n_in,
                              void* d_out, int out_size, void* d_ws, size_t ws_size,
                              hipStream_t stream) {
    const float* x   = (const float*)d_in[0];
    const int*   ei  = (const int*)d_in[1];
    const float* W1  = (const float*)d_in[2];
    const float* a1s = (const float*)d_in[3];
    const float* a1d = (const float*)d_in[4];
    const float* b1  = (const float*)d_in[5];
    const float* g1  = (const float*)d_in[6];
    const float* be1 = (const float*)d_in[7];
    const float* W2  = (const float*)d_in[8];
    const float* a2s = (const float*)d_in[9];
    const float* a2d = (const float*)d_in[10];
    const float* b2  = (const float*)d_in[11];
    const float* g2  = (const float*)d_in[12];
    const float* be2 = (const float*)d_in[13];
    const float* lW1 = (const float*)d_in[14];
    const float* lb1 = (const float*)d_in[15];
    const float* lW2 = (const float*)d_in[16];
    const float* lb2 = (const float*)d_in[17];
    float* out = (float*)d_out;

    char* p = (char*)d_ws;
    auto alloc = [&](size_t bytes) {
        char* r = p;
        p += (bytes + 255) & ~(size_t)255;
        return r;
    };
    unsigned short* h_bf  = (unsigned short*)alloc((size_t)N_NODES * HC * 2);
    unsigned short* a_bf  = (unsigned short*)alloc((size_t)N_NODES * HC * 2);
    unsigned short* wt1   = (unsigned short*)alloc((size_t)IN_CH * HC * 2);
    unsigned short* wt2   = (unsigned short*)alloc((size_t)HC * HC * 2);
    float* f_out  = (float*)alloc((size_t)N_NODES * HC * 4);
    float* f_als  = (float*)alloc((size_t)N_NODES * HEADS * 4);
    float* f_ald  = (float*)alloc((size_t)N_NODES * HEADS * 4);
    float* f_dinv = (float*)alloc((size_t)N_NODES * HEADS * 4);
    float* f_ex   = (float*)alloc((size_t)EP * HEADS * 4);
    int*   i_deg  = (int*)alloc((size_t)N_NODES * 4);
    int*   i_rs   = (int*)alloc((size_t)(N_NODES + 1) * 4);
    int*   i_cur  = (int*)alloc((size_t)N_NODES * 4);
    int*   i_src  = (int*)alloc((size_t)EP * 4);
    float* f_bns  = (float*)alloc(HC * 4);
    float* f_bnq  = (float*)alloc(HC * 4);
    float* f_sc1  = (float*)alloc(HC * 4);
    float* f_sh1  = (float*)alloc(HC * 4);
    float* f_sc2  = (float*)alloc(HC * 4);
    float* f_sh2  = (float*)alloc(HC * 4);

    int eb = (EP + 255) / 256;

    // ---- CSR build (same graph both layers) ----
    hipMemsetAsync(i_deg, 0, (size_t)N_NODES * 4, stream);
    deg_kernel<<<eb, 256, 0, stream>>>(ei, i_deg);
    scan_kernel<<<1, 1024, 0, stream>>>(i_deg, i_rs, i_cur);
    scatter_kernel<<<eb, 256, 0, stream>>>(ei, i_cur, i_src);

    // ---- weight conversion/transpose ----
    wt_kernel<<<(IN_CH * HC + 255) / 256, 256, 0, stream>>>(W1, wt1, IN_CH);
    wt_kernel<<<(HC * HC + 255) / 256, 256, 0, stream>>>(W2, wt2, HC);
    // ---- x -> bf16 ----
    cvt_kernel<<<(N_NODES * IN_CH + 255) / 256, 256, 0, stream>>>(x, nullptr, nullptr, a_bf,
                                                                  N_NODES * IN_CH);

    int gblocks = (N_NODES + 63) / 64;

    auto run_layer = [&](int K, const unsigned short* wt, const float* as_,
                         const float* ad_, const float* bias, const float* gam,
                         const float* bet, float* out_sc, float* out_sh) {
        gemm_mfma<<<gblocks, 256, 0, stream>>>(a_bf, wt, h_bf, N_NODES, K);
        al_kernel<<<N_NODES / 4, 256, 0, stream>>>(h_bf, as_, ad_, f_als, f_ald);
        logits_kernel<<<N_NODES / 4, 256, 0, stream>>>(i_src, i_rs, f_als, f_ald, f_ex,
                                                       f_dinv);
        aggregate_kernel<<<N_NODES / 4, 256, 0, stream>>>((const ushort4*)h_bf, f_ex, f_dinv,
                                                          i_rs, i_src, (const float4*)bias,
                                                          (float4*)f_out);
        hipMemsetAsync(f_bns, 0, HC * 4, stream);
        hipMemsetAsync(f_bnq, 0, HC * 4, stream);
        bnstat_kernel<<<(N_NODES + BN_ROWS - 1) / BN_ROWS, 256, 0, stream>>>(f_out, f_bns,
                                                                             f_bnq);
        bn_fin_kernel<<<1, 256, 0, stream>>>(f_bns, f_bnq, gam, bet, out_sc, out_sh);
    };

    run_layer(IN_CH, wt1, a1s, a1d, b1, g1, be1, f_sc1, f_sh1);
    // ---- BN(layer1 out) -> bf16 A for layer 2 ----
    cvt_kernel<<<(N_NODES * HC + 255) / 256, 256, 0, stream>>>(f_out, f_sc1, f_sh1, a_bf,
                                                               N_NODES * HC);
    run_layer(HC, wt2, a2s, a2d, b2, g2, be2, f_sc2, f_sh2);

    mlp_kernel<<<N_NODES / 8, 256, 0, stream>>>(f_out, f_sc2, f_sh2, lW1, lb1, lW2, lb2, out);
}

// Round 5
// 453.219 us; speedup vs baseline: 3.5598x; 1.1116x over previous
//
#include <hip/hip_runtime.h>
#include <math.h>

#define N_NODES 30000
#define E_EDGES 480000
#define EP (E_EDGES + N_NODES) /* 510000 edges incl self loops */
#define IN_CH 128
#define HID 32
#define HEADS 8
#define HC 256
#define BN_EPS 1e-5f
#define NEG_SLOPE 0.2f

typedef __attribute__((ext_vector_type(8))) short bf16x8;
typedef __attribute__((ext_vector_type(4))) float f32x4;

__device__ __forceinline__ float elu_f(float x) { return x > 0.f ? x : __expf(x) - 1.f; }
__device__ __forceinline__ float lrelu_f(float x) { return x >= 0.f ? x : NEG_SLOPE * x; }
__device__ __forceinline__ float bf2f(unsigned short u) {
    return __uint_as_float(((unsigned)u) << 16);
}
__device__ __forceinline__ unsigned short f2bf(float f) {
    unsigned u = __float_as_uint(f);
    return (unsigned short)((u + 0x7fffu + ((u >> 16) & 1u)) >> 16);
}

// ---------------- W[k][n] fp32 -> Wt[n][k] bf16 (n = col, NC cols, NC=2^ncshift) ----
__global__ void wt_kernel(const float* __restrict__ W, unsigned short* __restrict__ Wt,
                          int K, int ncshift) {
    int i = blockIdx.x * 256 + threadIdx.x;
    if (i >= (K << ncshift)) return;
    int k = i >> ncshift, n = i & ((1 << ncshift) - 1);
    Wt[(size_t)n * K + k] = f2bf(W[i]);
}

// ---------------- MFMA GEMM: C[M,256] = BN(A[M,K]) * Wt^T, fp32 A in, bf16 out ------
// block = 256 thr = 4 waves; tile 64(M) x 256(N), BK=32.
// A staged from fp32 with optional per-column scale/shift (fused BN of prev layer),
// converted to bf16 in registers. LDS rows padded to 40 bf16 (2-way bank alias only).
__global__ __launch_bounds__(256) void gemm_mfma(const float* __restrict__ A,
                                                 const unsigned short* __restrict__ Bt,
                                                 unsigned short* __restrict__ C,
                                                 int M, int K,
                                                 const float* __restrict__ sc,
                                                 const float* __restrict__ sh) {
    __shared__ __align__(16) unsigned short As[64][40];
    __shared__ __align__(16) unsigned short Bs[256][40];
    int tid = threadIdx.x;
    int wave = tid >> 6, lane = tid & 63;
    int m = lane & 15, q = lane >> 4;
    int row0 = blockIdx.x * 64;
    f32x4 acc[16];
#pragma unroll
    for (int i = 0; i < 16; ++i) acc[i] = (f32x4){0.f, 0.f, 0.f, 0.f};
    int ar = tid >> 2, aseg = tid & 3;
    for (int k0 = 0; k0 < K; k0 += 32) {
        float4 v0 = make_float4(0.f, 0.f, 0.f, 0.f), v1 = v0;
        int gr = row0 + ar;
        int c0 = k0 + aseg * 8;
        if (gr < M) {
            const float* ap = A + (size_t)gr * K + c0;
            v0 = *(const float4*)ap;
            v1 = *(const float4*)(ap + 4);
        }
        if (sc) {
            float4 s0 = *(const float4*)(sc + c0), s1 = *(const float4*)(sc + c0 + 4);
            float4 t0 = *(const float4*)(sh + c0), t1 = *(const float4*)(sh + c0 + 4);
            v0.x = v0.x * s0.x + t0.x; v0.y = v0.y * s0.y + t0.y;
            v0.z = v0.z * s0.z + t0.z; v0.w = v0.w * s0.w + t0.w;
            v1.x = v1.x * s1.x + t1.x; v1.y = v1.y * s1.y + t1.y;
            v1.z = v1.z * s1.z + t1.z; v1.w = v1.w * s1.w + t1.w;
        }
        bf16x8 av;
        av[0] = (short)f2bf(v0.x); av[1] = (short)f2bf(v0.y);
        av[2] = (short)f2bf(v0.z); av[3] = (short)f2bf(v0.w);
        av[4] = (short)f2bf(v1.x); av[5] = (short)f2bf(v1.y);
        av[6] = (short)f2bf(v1.z); av[7] = (short)f2bf(v1.w);
        *(bf16x8*)(&As[ar][aseg * 8]) = av;
        const unsigned short* bp = Bt + (size_t)tid * K + k0;
#pragma unroll
        for (int sg = 0; sg < 4; ++sg)
            *(uint4*)(&Bs[tid][sg * 8]) = *(const uint4*)(bp + sg * 8);
        __syncthreads();
        bf16x8 a = *(const bf16x8*)(&As[wave * 16 + m][q * 8]);
#pragma unroll
        for (int nt = 0; nt < 16; ++nt) {
            bf16x8 b = *(const bf16x8*)(&Bs[nt * 16 + m][q * 8]);
            acc[nt] = __builtin_amdgcn_mfma_f32_16x16x32_bf16(a, b, acc[nt], 0, 0, 0);
        }
        __syncthreads();
    }
#pragma unroll
    for (int nt = 0; nt < 16; ++nt) {
#pragma unroll
        for (int r = 0; r < 4; ++r) {
            int grow = row0 + wave * 16 + q * 4 + r;
            if (grow < M) C[(size_t)grow * HC + nt * 16 + m] = f2bf(acc[nt][r]);
        }
    }
}

// ---------------- attention logits per node (bf16 h) ----------------
__global__ __launch_bounds__(256) void al_kernel(const unsigned short* __restrict__ h,
                                                 const float* __restrict__ a_src,
                                                 const float* __restrict__ a_dst,
                                                 float* __restrict__ al_s,
                                                 float* __restrict__ al_d) {
    int lane = threadIdx.x & 63;
    int n = blockIdx.x * 4 + (threadIdx.x >> 6);
    const ushort4* row = (const ushort4*)(h + (size_t)n * HC);
    ushort4 rv = row[lane];
    int c0 = lane * 4;
    float ps = 0.f, pd = 0.f;
    float v0 = bf2f(rv.x), v1 = bf2f(rv.y), v2 = bf2f(rv.z), v3 = bf2f(rv.w);
    ps = v0 * a_src[c0] + v1 * a_src[c0 + 1] + v2 * a_src[c0 + 2] + v3 * a_src[c0 + 3];
    pd = v0 * a_dst[c0] + v1 * a_dst[c0 + 1] + v2 * a_dst[c0 + 2] + v3 * a_dst[c0 + 3];
#pragma unroll
    for (int off = 4; off >= 1; off >>= 1) {
        ps += __shfl_down(ps, off, 8);
        pd += __shfl_down(pd, off, 8);
    }
    if ((lane & 7) == 0) {
        al_s[n * HEADS + (lane >> 3)] = ps;
        al_d[n * HEADS + (lane >> 3)] = pd;
    }
}

// ---------------- CSR build (by dst) ----------------
__global__ void deg_kernel(const int* __restrict__ ei, int* __restrict__ deg) {
    int e = blockIdx.x * blockDim.x + threadIdx.x;
    if (e >= EP) return;
    int d = (e < E_EDGES) ? ei[E_EDGES + e] : e - E_EDGES;
    atomicAdd(deg + d, 1);
}

__global__ __launch_bounds__(1024) void scan_kernel(const int* __restrict__ deg,
                                                    int* __restrict__ row_start,
                                                    int* __restrict__ cursor) {
    __shared__ int sh[1024];
    __shared__ int carry_s;
    if (threadIdx.x == 0) carry_s = 0;
    __syncthreads();
    for (int base = 0; base < N_NODES; base += 1024) {
        int i = base + threadIdx.x;
        int v = (i < N_NODES) ? deg[i] : 0;
        sh[threadIdx.x] = v;
        __syncthreads();
        for (int off = 1; off < 1024; off <<= 1) {
            int t = (threadIdx.x >= off) ? sh[threadIdx.x - off] : 0;
            __syncthreads();
            sh[threadIdx.x] += t;
            __syncthreads();
        }
        int excl = carry_s + sh[threadIdx.x] - v;
        if (i < N_NODES) { row_start[i] = excl; cursor[i] = excl; }
        int total = sh[1023];
        __syncthreads();
        if (threadIdx.x == 0) carry_s += total;
        __syncthreads();
    }
    if (threadIdx.x == 0) row_start[N_NODES] = carry_s;
}

__global__ void scatter_kernel(const int* __restrict__ ei, int* __restrict__ cursor,
                               int* __restrict__ csr_src) {
    int e = blockIdx.x * blockDim.x + threadIdx.x;
    if (e >= EP) return;
    int s, d;
    if (e < E_EDGES) { s = ei[e]; d = ei[E_EDGES + e]; } else { s = d = e - E_EDGES; }
    int pos = atomicAdd(cursor + d, 1);
    csr_src[pos] = s;
}

// ---------------- per-dst softmax over CSR adjacency (no atomics) ----------------
__global__ __launch_bounds__(256) void logits_kernel(const int* __restrict__ csr_src,
                                                     const int* __restrict__ row_start,
                                                     const float* __restrict__ al_s,
                                                     const float* __restrict__ al_d,
                                                     float* __restrict__ csr_ex,
                                                     float* __restrict__ dinv) {
    int d = blockIdx.x * 4 + (threadIdx.x >> 6);
    int lane = threadIdx.x & 63;
    int h = lane & 7, eo = lane >> 3;
    int beg = row_start[d], end = row_start[d + 1];
    float ad = al_d[d * HEADS + h];
    float m = -1e30f;
    for (int i = beg + eo; i < end; i += 8) {
        int s = csr_src[i];
        m = fmaxf(m, lrelu_f(al_s[s * HEADS + h] + ad));
    }
    m = fmaxf(m, __shfl_xor(m, 8));
    m = fmaxf(m, __shfl_xor(m, 16));
    m = fmaxf(m, __shfl_xor(m, 32));
    float ssum = 0.f;
    for (int i = beg + eo; i < end; i += 8) {
        int s = csr_src[i];
        float x = __expf(lrelu_f(al_s[s * HEADS + h] + ad) - m);
        csr_ex[(size_t)i * HEADS + h] = x;
        ssum += x;
    }
    ssum += __shfl_xor(ssum, 8);
    ssum += __shfl_xor(ssum, 16);
    ssum += __shfl_xor(ssum, 32);
    if (eo == 0) dinv[d * HEADS + h] = 1.f / ssum;
}

// ---------------- aggregation + bias + ELU (bf16 h gather) ----------------
__global__ __launch_bounds__(256) void aggregate_kernel(const ushort4* __restrict__ h4,
                                                        const float* __restrict__ csr_ex,
                                                        const float* __restrict__ dinv,
                                                        const int* __restrict__ row_start,
                                                        const int* __restrict__ csr_src,
                                                        const float4* __restrict__ bias4,
                                                        float4* __restrict__ out4) {
    int d = blockIdx.x * 4 + (threadIdx.x >> 6);
    int lane = threadIdx.x & 63;
    int head = lane >> 3;
    int beg = row_start[d], end = row_start[d + 1];
    float inv = dinv[d * HEADS + head];
    float4 acc = make_float4(0.f, 0.f, 0.f, 0.f);
    int i = beg;
    for (; i + 4 <= end; i += 4) {
        int s0 = csr_src[i + 0];
        int s1 = csr_src[i + 1];
        int s2 = csr_src[i + 2];
        int s3 = csr_src[i + 3];
        float a0 = csr_ex[(size_t)(i + 0) * HEADS + head];
        float a1 = csr_ex[(size_t)(i + 1) * HEADS + head];
        float a2 = csr_ex[(size_t)(i + 2) * HEADS + head];
        float a3 = csr_ex[(size_t)(i + 3) * HEADS + head];
        ushort4 v0 = h4[(size_t)s0 * 64 + lane];
        ushort4 v1 = h4[(size_t)s1 * 64 + lane];
        ushort4 v2 = h4[(size_t)s2 * 64 + lane];
        ushort4 v3 = h4[(size_t)s3 * 64 + lane];
        acc.x += a0 * bf2f(v0.x) + a1 * bf2f(v1.x) + a2 * bf2f(v2.x) + a3 * bf2f(v3.x);
        acc.y += a0 * bf2f(v0.y) + a1 * bf2f(v1.y) + a2 * bf2f(v2.y) + a3 * bf2f(v3.y);
        acc.z += a0 * bf2f(v0.z) + a1 * bf2f(v1.z) + a2 * bf2f(v2.z) + a3 * bf2f(v3.z);
        acc.w += a0 * bf2f(v0.w) + a1 * bf2f(v1.w) + a2 * bf2f(v2.w) + a3 * bf2f(v3.w);
    }
    for (; i < end; ++i) {
        int s = csr_src[i];
        float a = csr_ex[(size_t)i * HEADS + head];
        ushort4 v = h4[(size_t)s * 64 + lane];
        acc.x += a * bf2f(v.x);
        acc.y += a * bf2f(v.y);
        acc.z += a * bf2f(v.z);
        acc.w += a * bf2f(v.w);
    }
    float4 b = bias4[lane];
    float4 r;
    r.x = elu_f(acc.x * inv + b.x);
    r.y = elu_f(acc.y * inv + b.y);
    r.z = elu_f(acc.z * inv + b.z);
    r.w = elu_f(acc.w * inv + b.w);
    out4[(size_t)d * 64 + lane] = r;
}

// ---------------- BN stats (read-only) ----------------
#define BN_ROWS 128
__global__ __launch_bounds__(256) void bnstat_kernel(const float* __restrict__ buf,
                                                     float* __restrict__ bnsum,
                                                     float* __restrict__ bnsq) {
    int c = threadIdx.x;
    int r0 = blockIdx.x * BN_ROWS;
    int rend = min(r0 + BN_ROWS, N_NODES);
    float s = 0.f, q = 0.f;
    for (int r = r0; r < rend; ++r) {
        float v = buf[(size_t)r * HC + c];
        s += v;
        q += v * v;
    }
    atomicAdd(bnsum + c, s);
    atomicAdd(bnsq + c, q);
}

__global__ void bn_fin_kernel(const float* __restrict__ bnsum, const float* __restrict__ bnsq,
                              const float* __restrict__ g, const float* __restrict__ be,
                              float* __restrict__ scale, float* __restrict__ shift) {
    int c = threadIdx.x;
    float m = bnsum[c] / (float)N_NODES;
    float var = bnsq[c] / (float)N_NODES - m * m;
    float istd = rsqrtf(var + BN_EPS);
    float sc = istd * g[c];
    scale[c] = sc;
    shift[c] = be[c] - m * sc;
}

// ---------------- MLP head via MFMA ----------------
// C[N,32] = BN2(in[N,256]) @ lW1, then out[n] = elu(C+lb1) @ lW2 + lb2.
// block = 256 thr = 4 waves; wave handles 16 rows, both 16-col tiles.
// Wt = lW1 transposed [32][256] bf16; A-fragment built from fp32 with BN fused.
__global__ __launch_bounds__(256) void mlp_mfma(const float* __restrict__ in,
                                                const float* __restrict__ sc,
                                                const float* __restrict__ sh,
                                                const unsigned short* __restrict__ Wt,
                                                const float* __restrict__ lb1,
                                                const float* __restrict__ lW2,
                                                const float* __restrict__ lb2,
                                                float* __restrict__ out) {
    int tid = threadIdx.x;
    int wave = tid >> 6, lane = tid & 63;
    int m = lane & 15, q = lane >> 4;
    int rbase = blockIdx.x * 64 + wave * 16;
    int arow = rbase + m;
    bool valid = arow < N_NODES;
    const float* ap = in + (size_t)arow * HC;
    f32x4 acc0 = (f32x4){0.f, 0.f, 0.f, 0.f}, acc1 = acc0;
#pragma unroll
    for (int k0 = 0; k0 < HC; k0 += 32) {
        int c0 = k0 + q * 8;
        bf16x8 a = (bf16x8){0, 0, 0, 0, 0, 0, 0, 0};
        if (valid) {
            float4 v0 = *(const float4*)(ap + c0);
            float4 v1 = *(const float4*)(ap + c0 + 4);
            float4 s0 = *(const float4*)(sc + c0), s1 = *(const float4*)(sc + c0 + 4);
            float4 t0 = *(const float4*)(sh + c0), t1 = *(const float4*)(sh + c0 + 4);
            a[0] = (short)f2bf(v0.x * s0.x + t0.x);
            a[1] = (short)f2bf(v0.y * s0.y + t0.y);
            a[2] = (short)f2bf(v0.z * s0.z + t0.z);
            a[3] = (short)f2bf(v0.w * s0.w + t0.w);
            a[4] = (short)f2bf(v1.x * s1.x + t1.x);
            a[5] = (short)f2bf(v1.y * s1.y + t1.y);
            a[6] = (short)f2bf(v1.z * s1.z + t1.z);
            a[7] = (short)f2bf(v1.w * s1.w + t1.w);
        }
        bf16x8 b0 = *(const bf16x8*)(Wt + (size_t)m * HC + c0);
        bf16x8 b1 = *(const bf16x8*)(Wt + (size_t)(m + 16) * HC + c0);
        acc0 = __builtin_amdgcn_mfma_f32_16x16x32_bf16(a, b0, acc0, 0, 0, 0);
        acc1 = __builtin_amdgcn_mfma_f32_16x16x32_bf16(a, b1, acc1, 0, 0, 0);
    }
    float w2a = lW2[m], w2b = lW2[m + 16];
    float ba = lb1[m], bb = lb1[m + 16];
#pragma unroll
    for (int r = 0; r < 4; ++r) {
        float v = elu_f(acc0[r] + ba) * w2a + elu_f(acc1[r] + bb) * w2b;
        v += __shfl_xor(v, 1);
        v += __shfl_xor(v, 2);
        v += __shfl_xor(v, 4);
        v += __shfl_xor(v, 8);
        int orow = rbase + q * 4 + r;
        if (m == 0 && orow < N_NODES) out[orow] = v + lb2[0];
    }
}

extern "C" void kernel_launch(void* const* d_in, const int* in_sizes, int n_in,
                              void* d_out, int out_size, void* d_ws, size_t ws_size,
                              hipStream_t stream) {
    const float* x   = (const float*)d_in[0];
    const int*   ei  = (const int*)d_in[1];
    const float* W1  = (const float*)d_in[2];
    const float* a1s = (const float*)d_in[3];
    const float* a1d = (const float*)d_in[4];
    const float* b1  = (const float*)d_in[5];
    const float* g1  = (const float*)d_in[6];
    const float* be1 = (const float*)d_in[7];
    const float* W2  = (const float*)d_in[8];
    const float* a2s = (const float*)d_in[9];
    const float* a2d = (const float*)d_in[10];
    const float* b2  = (const float*)d_in[11];
    const float* g2  = (const float*)d_in[12];
    const float* be2 = (const float*)d_in[13];
    const float* lW1 = (const float*)d_in[14];
    const float* lb1 = (const float*)d_in[15];
    const float* lW2 = (const float*)d_in[16];
    const float* lb2 = (const float*)d_in[17];
    float* out = (float*)d_out;

    char* p = (char*)d_ws;
    auto alloc = [&](size_t bytes) {
        char* r = p;
        p += (bytes + 255) & ~(size_t)255;
        return r;
    };
    unsigned short* h_bf  = (unsigned short*)alloc((size_t)N_NODES * HC * 2);
    unsigned short* wt1   = (unsigned short*)alloc((size_t)IN_CH * HC * 2);
    unsigned short* wt2   = (unsigned short*)alloc((size_t)HC * HC * 2);
    unsigned short* wtm   = (unsigned short*)alloc((size_t)HC * HID * 2);
    float* f_out  = (float*)alloc((size_t)N_NODES * HC * 4);
    float* f_als  = (float*)alloc((size_t)N_NODES * HEADS * 4);
    float* f_ald  = (float*)alloc((size_t)N_NODES * HEADS * 4);
    float* f_dinv = (float*)alloc((size_t)N_NODES * HEADS * 4);
    float* f_ex   = (float*)alloc((size_t)EP * HEADS * 4);
    int*   i_deg  = (int*)alloc((size_t)N_NODES * 4);
    int*   i_rs   = (int*)alloc((size_t)(N_NODES + 1) * 4);
    int*   i_cur  = (int*)alloc((size_t)N_NODES * 4);
    int*   i_src  = (int*)alloc((size_t)EP * 4);
    float* f_bns  = (float*)alloc(HC * 4);
    float* f_bnq  = (float*)alloc(HC * 4);
    float* f_sc1  = (float*)alloc(HC * 4);
    float* f_sh1  = (float*)alloc(HC * 4);
    float* f_sc2  = (float*)alloc(HC * 4);
    float* f_sh2  = (float*)alloc(HC * 4);

    int eb = (EP + 255) / 256;

    // ---- CSR build (same graph both layers) ----
    hipMemsetAsync(i_deg, 0, (size_t)N_NODES * 4, stream);
    deg_kernel<<<eb, 256, 0, stream>>>(ei, i_deg);
    scan_kernel<<<1, 1024, 0, stream>>>(i_deg, i_rs, i_cur);
    scatter_kernel<<<eb, 256, 0, stream>>>(ei, i_cur, i_src);

    // ---- weight conversion/transpose ----
    wt_kernel<<<(IN_CH * HC + 255) / 256, 256, 0, stream>>>(W1, wt1, IN_CH, 8);
    wt_kernel<<<(HC * HC + 255) / 256, 256, 0, stream>>>(W2, wt2, HC, 8);
    wt_kernel<<<(HC * HID + 255) / 256, 256, 0, stream>>>(lW1, wtm, HC, 5);

    int gblocks = (N_NODES + 63) / 64;

    auto run_layer = [&](const float* Ain, int K, const unsigned short* wt,
                         const float* in_sc, const float* in_sh, const float* as_,
                         const float* ad_, const float* bias, const float* gam,
                         const float* bet, float* out_sc, float* out_sh) {
        gemm_mfma<<<gblocks, 256, 0, stream>>>(Ain, wt, h_bf, N_NODES, K, in_sc, in_sh);
        al_kernel<<<N_NODES / 4, 256, 0, stream>>>(h_bf, as_, ad_, f_als, f_ald);
        logits_kernel<<<N_NODES / 4, 256, 0, stream>>>(i_src, i_rs, f_als, f_ald, f_ex,
                                                       f_dinv);
        aggregate_kernel<<<N_NODES / 4, 256, 0, stream>>>((const ushort4*)h_bf, f_ex, f_dinv,
                                                          i_rs, i_src, (const float4*)bias,
                                                          (float4*)f_out);
        hipMemsetAsync(f_bns, 0, HC * 4, stream);
        hipMemsetAsync(f_bnq, 0, HC * 4, stream);
        bnstat_kernel<<<(N_NODES + BN_ROWS - 1) / BN_ROWS, 256, 0, stream>>>(f_out, f_bns,
                                                                             f_bnq);
        bn_fin_kernel<<<1, 256, 0, stream>>>(f_bns, f_bnq, gam, bet, out_sc, out_sh);
    };

    run_layer(x, IN_CH, wt1, nullptr, nullptr, a1s, a1d, b1, g1, be1, f_sc1, f_sh1);
    run_layer(f_out, HC, wt2, f_sc1, f_sh1, a2s, a2d, b2, g2, be2, f_sc2, f_sh2);

    mlp_mfma<<<gblocks, 256, 0, stream>>>(f_out, f_sc2, f_sh2, wtm, lb1, lW2, lb2, out);
}

// Round 6
// 403.310 us; speedup vs baseline: 4.0003x; 1.1237x over previous
//
#include <hip/hip_runtime.h>
#include <math.h>

#define N_NODES 30000
#define E_EDGES 480000
#define EP (E_EDGES + N_NODES) /* 510000 edges incl self loops */
#define IN_CH 128
#define HID 32
#define HEADS 8
#define HC 256
#define BN_EPS 1e-5f
#define NEG_SLOPE 0.2f
#define SCAN_NB ((N_NODES + 1023) / 1024) /* 30 */

typedef __attribute__((ext_vector_type(8))) short bf16x8;
typedef __attribute__((ext_vector_type(4))) float f32x4;

__device__ __forceinline__ float elu_f(float x) { return x > 0.f ? x : __expf(x) - 1.f; }
__device__ __forceinline__ float lrelu_f(float x) { return x >= 0.f ? x : NEG_SLOPE * x; }
__device__ __forceinline__ float bf2f(unsigned short u) {
    return __uint_as_float(((unsigned)u) << 16);
}
__device__ __forceinline__ unsigned short f2bf(float f) {
    unsigned u = __float_as_uint(f);
    return (unsigned short)((u + 0x7fffu + ((u >> 16) & 1u)) >> 16);
}

// ---------------- W[k][n] fp32 -> Wt[n][k] bf16 (n = col, NC cols, NC=2^ncshift) ----
__global__ void wt_kernel(const float* __restrict__ W, unsigned short* __restrict__ Wt,
                          int K, int ncshift) {
    int i = blockIdx.x * 256 + threadIdx.x;
    if (i >= (K << ncshift)) return;
    int k = i >> ncshift, n = i & ((1 << ncshift) - 1);
    Wt[(size_t)n * K + k] = f2bf(W[i]);
}

// ---------------- MFMA GEMM: C[M,256] = BN(A[M,K]) * Wt^T, fp32 A in, bf16 out ------
__global__ __launch_bounds__(256) void gemm_mfma(const float* __restrict__ A,
                                                 const unsigned short* __restrict__ Bt,
                                                 unsigned short* __restrict__ C,
                                                 int M, int K,
                                                 const float* __restrict__ sc,
                                                 const float* __restrict__ sh) {
    __shared__ __align__(16) unsigned short As[64][40];
    __shared__ __align__(16) unsigned short Bs[256][40];
    int tid = threadIdx.x;
    int wave = tid >> 6, lane = tid & 63;
    int m = lane & 15, q = lane >> 4;
    int row0 = blockIdx.x * 64;
    f32x4 acc[16];
#pragma unroll
    for (int i = 0; i < 16; ++i) acc[i] = (f32x4){0.f, 0.f, 0.f, 0.f};
    int ar = tid >> 2, aseg = tid & 3;
    for (int k0 = 0; k0 < K; k0 += 32) {
        float4 v0 = make_float4(0.f, 0.f, 0.f, 0.f), v1 = v0;
        int gr = row0 + ar;
        int c0 = k0 + aseg * 8;
        if (gr < M) {
            const float* ap = A + (size_t)gr * K + c0;
            v0 = *(const float4*)ap;
            v1 = *(const float4*)(ap + 4);
        }
        if (sc) {
            float4 s0 = *(const float4*)(sc + c0), s1 = *(const float4*)(sc + c0 + 4);
            float4 t0 = *(const float4*)(sh + c0), t1 = *(const float4*)(sh + c0 + 4);
            v0.x = v0.x * s0.x + t0.x; v0.y = v0.y * s0.y + t0.y;
            v0.z = v0.z * s0.z + t0.z; v0.w = v0.w * s0.w + t0.w;
            v1.x = v1.x * s1.x + t1.x; v1.y = v1.y * s1.y + t1.y;
            v1.z = v1.z * s1.z + t1.z; v1.w = v1.w * s1.w + t1.w;
        }
        bf16x8 av;
        av[0] = (short)f2bf(v0.x); av[1] = (short)f2bf(v0.y);
        av[2] = (short)f2bf(v0.z); av[3] = (short)f2bf(v0.w);
        av[4] = (short)f2bf(v1.x); av[5] = (short)f2bf(v1.y);
        av[6] = (short)f2bf(v1.z); av[7] = (short)f2bf(v1.w);
        *(bf16x8*)(&As[ar][aseg * 8]) = av;
        const unsigned short* bp = Bt + (size_t)tid * K + k0;
#pragma unroll
        for (int sg = 0; sg < 4; ++sg)
            *(uint4*)(&Bs[tid][sg * 8]) = *(const uint4*)(bp + sg * 8);
        __syncthreads();
        bf16x8 a = *(const bf16x8*)(&As[wave * 16 + m][q * 8]);
#pragma unroll
        for (int nt = 0; nt < 16; ++nt) {
            bf16x8 b = *(const bf16x8*)(&Bs[nt * 16 + m][q * 8]);
            acc[nt] = __builtin_amdgcn_mfma_f32_16x16x32_bf16(a, b, acc[nt], 0, 0, 0);
        }
        __syncthreads();
    }
#pragma unroll
    for (int nt = 0; nt < 16; ++nt) {
#pragma unroll
        for (int r = 0; r < 4; ++r) {
            int grow = row0 + wave * 16 + q * 4 + r;
            if (grow < M) C[(size_t)grow * HC + nt * 16 + m] = f2bf(acc[nt][r]);
        }
    }
}

// ---------------- attention logits per node (bf16 h) ----------------
__global__ __launch_bounds__(256) void al_kernel(const unsigned short* __restrict__ h,
                                                 const float* __restrict__ a_src,
                                                 const float* __restrict__ a_dst,
                                                 float* __restrict__ al_s,
                                                 float* __restrict__ al_d) {
    int lane = threadIdx.x & 63;
    int n = blockIdx.x * 4 + (threadIdx.x >> 6);
    const ushort4* row = (const ushort4*)(h + (size_t)n * HC);
    ushort4 rv = row[lane];
    int c0 = lane * 4;
    float ps = 0.f, pd = 0.f;
    float v0 = bf2f(rv.x), v1 = bf2f(rv.y), v2 = bf2f(rv.z), v3 = bf2f(rv.w);
    ps = v0 * a_src[c0] + v1 * a_src[c0 + 1] + v2 * a_src[c0 + 2] + v3 * a_src[c0 + 3];
    pd = v0 * a_dst[c0] + v1 * a_dst[c0 + 1] + v2 * a_dst[c0 + 2] + v3 * a_dst[c0 + 3];
#pragma unroll
    for (int off = 4; off >= 1; off >>= 1) {
        ps += __shfl_down(ps, off, 8);
        pd += __shfl_down(pd, off, 8);
    }
    if ((lane & 7) == 0) {
        al_s[n * HEADS + (lane >> 3)] = ps;
        al_d[n * HEADS + (lane >> 3)] = pd;
    }
}

// ---------------- CSR build (by dst) ----------------
__global__ void deg_kernel(const int* __restrict__ ei, int* __restrict__ deg) {
    int e = blockIdx.x * blockDim.x + threadIdx.x;
    if (e >= EP) return;
    int d = (e < E_EDGES) ? ei[E_EDGES + e] : e - E_EDGES;
    atomicAdd(deg + d, 1);
}

// ---- 3-phase parallel scan ----
__global__ __launch_bounds__(1024) void scan_blk(const int* __restrict__ deg,
                                                 int* __restrict__ rs,
                                                 int* __restrict__ bsum) {
    __shared__ int sh[1024];
    int t = threadIdx.x;
    int i = blockIdx.x * 1024 + t;
    int v = (i < N_NODES) ? deg[i] : 0;
    sh[t] = v;
    __syncthreads();
    for (int off = 1; off < 1024; off <<= 1) {
        int tv = (t >= off) ? sh[t - off] : 0;
        __syncthreads();
        sh[t] += tv;
        __syncthreads();
    }
    if (i < N_NODES) rs[i] = sh[t] - v;  // local exclusive
    if (t == 1023) bsum[blockIdx.x] = sh[1023];
}

__global__ void scan_top(int* __restrict__ bsum) {
    int t = threadIdx.x;  // single wave of 64, SCAN_NB <= 64
    int v = (t < SCAN_NB) ? bsum[t] : 0;
    int s = v;
#pragma unroll
    for (int off = 1; off < 64; off <<= 1) {
        int u = __shfl_up(s, off);
        if (t >= off) s += u;
    }
    if (t < SCAN_NB) bsum[t] = s - v;          // exclusive block offsets
    if (t == SCAN_NB - 1) bsum[SCAN_NB] = s;   // grand total
}

__global__ __launch_bounds__(1024) void scan_add(int* __restrict__ rs,
                                                 int* __restrict__ cursor,
                                                 const int* __restrict__ bsum) {
    int i = blockIdx.x * 1024 + threadIdx.x;
    if (i < N_NODES) {
        int v = rs[i] + bsum[blockIdx.x];
        rs[i] = v;
        cursor[i] = v;
    } else if (i == N_NODES) {
        rs[N_NODES] = bsum[SCAN_NB];
    }
}

__global__ void scatter_kernel(const int* __restrict__ ei, int* __restrict__ cursor,
                               int* __restrict__ csr_src) {
    int e = blockIdx.x * blockDim.x + threadIdx.x;
    if (e >= EP) return;
    int s, d;
    if (e < E_EDGES) { s = ei[e]; d = ei[E_EDGES + e]; } else { s = d = e - E_EDGES; }
    int pos = atomicAdd(cursor + d, 1);
    csr_src[pos] = s;
}

// ---------------- per-dst softmax over CSR adjacency (no atomics) ----------------
__global__ __launch_bounds__(256) void logits_kernel(const int* __restrict__ csr_src,
                                                     const int* __restrict__ row_start,
                                                     const float* __restrict__ al_s,
                                                     const float* __restrict__ al_d,
                                                     float* __restrict__ csr_ex,
                                                     float* __restrict__ dinv) {
    int d = blockIdx.x * 4 + (threadIdx.x >> 6);
    int lane = threadIdx.x & 63;
    int h = lane & 7, eo = lane >> 3;
    int beg = row_start[d], end = row_start[d + 1];
    float ad = al_d[d * HEADS + h];
    float m = -1e30f;
    for (int i = beg + eo; i < end; i += 8) {
        int s = csr_src[i];
        m = fmaxf(m, lrelu_f(al_s[s * HEADS + h] + ad));
    }
    m = fmaxf(m, __shfl_xor(m, 8));
    m = fmaxf(m, __shfl_xor(m, 16));
    m = fmaxf(m, __shfl_xor(m, 32));
    float ssum = 0.f;
    for (int i = beg + eo; i < end; i += 8) {
        int s = csr_src[i];
        float x = __expf(lrelu_f(al_s[s * HEADS + h] + ad) - m);
        csr_ex[(size_t)i * HEADS + h] = x;
        ssum += x;
    }
    ssum += __shfl_xor(ssum, 8);
    ssum += __shfl_xor(ssum, 16);
    ssum += __shfl_xor(ssum, 32);
    if (eo == 0) dinv[d * HEADS + h] = 1.f / ssum;
}

// ---------------- aggregation + bias + ELU (bf16 h gather) ----------------
__global__ __launch_bounds__(256) void aggregate_kernel(const ushort4* __restrict__ h4,
                                                        const float* __restrict__ csr_ex,
                                                        const float* __restrict__ dinv,
                                                        const int* __restrict__ row_start,
                                                        const int* __restrict__ csr_src,
                                                        const float4* __restrict__ bias4,
                                                        float4* __restrict__ out4) {
    int d = blockIdx.x * 4 + (threadIdx.x >> 6);
    int lane = threadIdx.x & 63;
    int head = lane >> 3;
    int beg = row_start[d], end = row_start[d + 1];
    float inv = dinv[d * HEADS + head];
    float4 acc = make_float4(0.f, 0.f, 0.f, 0.f);
    int i = beg;
    for (; i + 4 <= end; i += 4) {
        int s0 = csr_src[i + 0];
        int s1 = csr_src[i + 1];
        int s2 = csr_src[i + 2];
        int s3 = csr_src[i + 3];
        float a0 = csr_ex[(size_t)(i + 0) * HEADS + head];
        float a1 = csr_ex[(size_t)(i + 1) * HEADS + head];
        float a2 = csr_ex[(size_t)(i + 2) * HEADS + head];
        float a3 = csr_ex[(size_t)(i + 3) * HEADS + head];
        ushort4 v0 = h4[(size_t)s0 * 64 + lane];
        ushort4 v1 = h4[(size_t)s1 * 64 + lane];
        ushort4 v2 = h4[(size_t)s2 * 64 + lane];
        ushort4 v3 = h4[(size_t)s3 * 64 + lane];
        acc.x += a0 * bf2f(v0.x) + a1 * bf2f(v1.x) + a2 * bf2f(v2.x) + a3 * bf2f(v3.x);
        acc.y += a0 * bf2f(v0.y) + a1 * bf2f(v1.y) + a2 * bf2f(v2.y) + a3 * bf2f(v3.y);
        acc.z += a0 * bf2f(v0.z) + a1 * bf2f(v1.z) + a2 * bf2f(v2.z) + a3 * bf2f(v3.z);
        acc.w += a0 * bf2f(v0.w) + a1 * bf2f(v1.w) + a2 * bf2f(v2.w) + a3 * bf2f(v3.w);
    }
    for (; i < end; ++i) {
        int s = csr_src[i];
        float a = csr_ex[(size_t)i * HEADS + head];
        ushort4 v = h4[(size_t)s * 64 + lane];
        acc.x += a * bf2f(v.x);
        acc.y += a * bf2f(v.y);
        acc.z += a * bf2f(v.z);
        acc.w += a * bf2f(v.w);
    }
    float4 b = bias4[lane];
    float4 r;
    r.x = elu_f(acc.x * inv + b.x);
    r.y = elu_f(acc.y * inv + b.y);
    r.z = elu_f(acc.z * inv + b.z);
    r.w = elu_f(acc.w * inv + b.w);
    out4[(size_t)d * 64 + lane] = r;
}

// ---------------- BN stats (read-only) ----------------
#define BN_ROWS 128
__global__ __launch_bounds__(256) void bnstat_kernel(const float* __restrict__ buf,
                                                     float* __restrict__ bnsum,
                                                     float* __restrict__ bnsq) {
    int c = threadIdx.x;
    int r0 = blockIdx.x * BN_ROWS;
    int rend = min(r0 + BN_ROWS, N_NODES);
    float s = 0.f, q = 0.f;
    for (int r = r0; r < rend; ++r) {
        float v = buf[(size_t)r * HC + c];
        s += v;
        q += v * v;
    }
    atomicAdd(bnsum + c, s);
    atomicAdd(bnsq + c, q);
}

__global__ void bn_fin_kernel(const float* __restrict__ bnsum, const float* __restrict__ bnsq,
                              const float* __restrict__ g, const float* __restrict__ be,
                              float* __restrict__ scale, float* __restrict__ shift) {
    int c = threadIdx.x;
    float m = bnsum[c] / (float)N_NODES;
    float var = bnsq[c] / (float)N_NODES - m * m;
    float istd = rsqrtf(var + BN_EPS);
    float sc = istd * g[c];
    scale[c] = sc;
    shift[c] = be[c] - m * sc;
}

// ---------------- MLP head via MFMA ----------------
__global__ __launch_bounds__(256) void mlp_mfma(const float* __restrict__ in,
                                                const float* __restrict__ sc,
                                                const float* __restrict__ sh,
                                                const unsigned short* __restrict__ Wt,
                                                const float* __restrict__ lb1,
                                                const float* __restrict__ lW2,
                                                const float* __restrict__ lb2,
                                                float* __restrict__ out) {
    int tid = threadIdx.x;
    int wave = tid >> 6, lane = tid & 63;
    int m = lane & 15, q = lane >> 4;
    int rbase = blockIdx.x * 64 + wave * 16;
    int arow = rbase + m;
    bool valid = arow < N_NODES;
    const float* ap = in + (size_t)arow * HC;
    f32x4 acc0 = (f32x4){0.f, 0.f, 0.f, 0.f}, acc1 = acc0;
#pragma unroll
    for (int k0 = 0; k0 < HC; k0 += 32) {
        int c0 = k0 + q * 8;
        bf16x8 a = (bf16x8){0, 0, 0, 0, 0, 0, 0, 0};
        if (valid) {
            float4 v0 = *(const float4*)(ap + c0);
            float4 v1 = *(const float4*)(ap + c0 + 4);
            float4 s0 = *(const float4*)(sc + c0), s1 = *(const float4*)(sc + c0 + 4);
            float4 t0 = *(const float4*)(sh + c0), t1 = *(const float4*)(sh + c0 + 4);
            a[0] = (short)f2bf(v0.x * s0.x + t0.x);
            a[1] = (short)f2bf(v0.y * s0.y + t0.y);
            a[2] = (short)f2bf(v0.z * s0.z + t0.z);
            a[3] = (short)f2bf(v0.w * s0.w + t0.w);
            a[4] = (short)f2bf(v1.x * s1.x + t1.x);
            a[5] = (short)f2bf(v1.y * s1.y + t1.y);
            a[6] = (short)f2bf(v1.z * s1.z + t1.z);
            a[7] = (short)f2bf(v1.w * s1.w + t1.w);
        }
        bf16x8 b0 = *(const bf16x8*)(Wt + (size_t)m * HC + c0);
        bf16x8 b1 = *(const bf16x8*)(Wt + (size_t)(m + 16) * HC + c0);
        acc0 = __builtin_amdgcn_mfma_f32_16x16x32_bf16(a, b0, acc0, 0, 0, 0);
        acc1 = __builtin_amdgcn_mfma_f32_16x16x32_bf16(a, b1, acc1, 0, 0, 0);
    }
    float w2a = lW2[m], w2b = lW2[m + 16];
    float ba = lb1[m], bb = lb1[m + 16];
#pragma unroll
    for (int r = 0; r < 4; ++r) {
        float v = elu_f(acc0[r] + ba) * w2a + elu_f(acc1[r] + bb) * w2b;
        v += __shfl_xor(v, 1);
        v += __shfl_xor(v, 2);
        v += __shfl_xor(v, 4);
        v += __shfl_xor(v, 8);
        int orow = rbase + q * 4 + r;
        if (m == 0 && orow < N_NODES) out[orow] = v + lb2[0];
    }
}

extern "C" void kernel_launch(void* const* d_in, const int* in_sizes, int n_in,
                              void* d_out, int out_size, void* d_ws, size_t ws_size,
                              hipStream_t stream) {
    const float* x   = (const float*)d_in[0];
    const int*   ei  = (const int*)d_in[1];
    const float* W1  = (const float*)d_in[2];
    const float* a1s = (const float*)d_in[3];
    const float* a1d = (const float*)d_in[4];
    const float* b1  = (const float*)d_in[5];
    const float* g1  = (const float*)d_in[6];
    const float* be1 = (const float*)d_in[7];
    const float* W2  = (const float*)d_in[8];
    const float* a2s = (const float*)d_in[9];
    const float* a2d = (const float*)d_in[10];
    const float* b2  = (const float*)d_in[11];
    const float* g2  = (const float*)d_in[12];
    const float* be2 = (const float*)d_in[13];
    const float* lW1 = (const float*)d_in[14];
    const float* lb1 = (const float*)d_in[15];
    const float* lW2 = (const float*)d_in[16];
    const float* lb2 = (const float*)d_in[17];
    float* out = (float*)d_out;

    char* p = (char*)d_ws;
    auto alloc = [&](size_t bytes) {
        char* r = p;
        p += (bytes + 255) & ~(size_t)255;
        return r;
    };
    unsigned short* h_bf  = (unsigned short*)alloc((size_t)N_NODES * HC * 2);
    unsigned short* wt1   = (unsigned short*)alloc((size_t)IN_CH * HC * 2);
    unsigned short* wt2   = (unsigned short*)alloc((size_t)HC * HC * 2);
    unsigned short* wtm   = (unsigned short*)alloc((size_t)HC * HID * 2);
    float* f_out  = (float*)alloc((size_t)N_NODES * HC * 4);
    float* f_als  = (float*)alloc((size_t)N_NODES * HEADS * 4);
    float* f_ald  = (float*)alloc((size_t)N_NODES * HEADS * 4);
    float* f_dinv = (float*)alloc((size_t)N_NODES * HEADS * 4);
    float* f_ex   = (float*)alloc((size_t)EP * HEADS * 4);
    int*   i_deg  = (int*)alloc((size_t)N_NODES * 4);
    int*   i_rs   = (int*)alloc((size_t)(N_NODES + 1) * 4);
    int*   i_cur  = (int*)alloc((size_t)N_NODES * 4);
    int*   i_src  = (int*)alloc((size_t)EP * 4);
    int*   i_bsum = (int*)alloc((size_t)(SCAN_NB + 1) * 4);
    float* f_bns  = (float*)alloc(HC * 4);
    float* f_bnq  = (float*)alloc(HC * 4);
    float* f_sc1  = (float*)alloc(HC * 4);
    float* f_sh1  = (float*)alloc(HC * 4);
    float* f_sc2  = (float*)alloc(HC * 4);
    float* f_sh2  = (float*)alloc(HC * 4);

    int eb = (EP + 255) / 256;

    // ---- CSR build (same graph both layers) ----
    hipMemsetAsync(i_deg, 0, (size_t)N_NODES * 4, stream);
    deg_kernel<<<eb, 256, 0, stream>>>(ei, i_deg);
    scan_blk<<<SCAN_NB, 1024, 0, stream>>>(i_deg, i_rs, i_bsum);
    scan_top<<<1, 64, 0, stream>>>(i_bsum);
    scan_add<<<SCAN_NB, 1024, 0, stream>>>(i_rs, i_cur, i_bsum);
    scatter_kernel<<<eb, 256, 0, stream>>>(ei, i_cur, i_src);

    // ---- weight conversion/transpose ----
    wt_kernel<<<(IN_CH * HC + 255) / 256, 256, 0, stream>>>(W1, wt1, IN_CH, 8);
    wt_kernel<<<(HC * HC + 255) / 256, 256, 0, stream>>>(W2, wt2, HC, 8);
    wt_kernel<<<(HC * HID + 255) / 256, 256, 0, stream>>>(lW1, wtm, HC, 5);

    int gblocks = (N_NODES + 63) / 64;

    auto run_layer = [&](const float* Ain, int K, const unsigned short* wt,
                         const float* in_sc, const float* in_sh, const float* as_,
                         const float* ad_, const float* bias, const float* gam,
                         const float* bet, float* out_sc, float* out_sh) {
        gemm_mfma<<<gblocks, 256, 0, stream>>>(Ain, wt, h_bf, N_NODES, K, in_sc, in_sh);
        al_kernel<<<N_NODES / 4, 256, 0, stream>>>(h_bf, as_, ad_, f_als, f_ald);
        logits_kernel<<<N_NODES / 4, 256, 0, stream>>>(i_src, i_rs, f_als, f_ald, f_ex,
                                                       f_dinv);
        aggregate_kernel<<<N_NODES / 4, 256, 0, stream>>>((const ushort4*)h_bf, f_ex, f_dinv,
                                                          i_rs, i_src, (const float4*)bias,
                                                          (float4*)f_out);
        hipMemsetAsync(f_bns, 0, HC * 4, stream);
        hipMemsetAsync(f_bnq, 0, HC * 4, stream);
        bnstat_kernel<<<(N_NODES + BN_ROWS - 1) / BN_ROWS, 256, 0, stream>>>(f_out, f_bns,
                                                                             f_bnq);
        bn_fin_kernel<<<1, 256, 0, stream>>>(f_bns, f_bnq, gam, bet, out_sc, out_sh);
    };

    run_layer(x, IN_CH, wt1, nullptr, nullptr, a1s, a1d, b1, g1, be1, f_sc1, f_sh1);
    run_layer(f_out, HC, wt2, f_sc1, f_sh1, a2s, a2d, b2, g2, be2, f_sc2, f_sh2);

    mlp_mfma<<<gblocks, 256, 0, stream>>>(f_out, f_sc2, f_sh2, wtm, lb1, lW2, lb2, out);
}